// Round 7
// baseline (1528.118 us; speedup 1.0000x reference)
//
#include <hip/hip_runtime.h>
#include <cmath>

// ---------------------------------------------------------------------------
// BiDirectionalAddFFBlock: LN -> mamba(fwd)+mamba(rev) -> gelu residual ->
// LN -> FFN.  B=4, L=2048, D=1024, di=2048, ds=16, dt_rank=64, DFF=4096.
// Round 13 (from R12 @ 1231us):
//  (1) x_proj was 64 blocks = 0.25/CU (latency-serialized K=2048 crawl).
//      Split-K x8: 512 blocks of 128x128x256 -> f32 partials + reduce.
//  (2) Bijective XCD-aware block swizzle (T1) on the five big GEMMs
//      (FETCH 57.6MB vs 24MB ideal = 2.4x L2 overfetch across XCDs).
// ---------------------------------------------------------------------------

namespace {

using u16 = unsigned short;
using uint = unsigned int;

constexpr int kB = 4;
constexpr int kL = 2048;
constexpr int kD = 1024;
constexpr int kDI = 2048;
constexpr int kDFF = 4096;
constexpr int kDS = 16;
constexpr int kDtRank = 64;
constexpr int kNPad = 128;       // x_proj N=96 padded to 128
constexpr int kM = kB * kL;      // 8192 rows
constexpr int kNCH = 64;         // scan chunks per segment

typedef short bf16x8 __attribute__((ext_vector_type(8)));
typedef float f32x4  __attribute__((ext_vector_type(4)));
typedef unsigned short ushort8 __attribute__((ext_vector_type(8)));

__device__ __forceinline__ float bf2f(u16 u) {
  union { unsigned int i; float f; } c; c.i = ((unsigned int)u) << 16; return c.f;
}
__device__ __forceinline__ u16 f2bf(float f) {  // round-to-nearest-even
  union { float f; unsigned int i; } c; c.f = f;
  return (u16)((c.i + 0x7FFFu + ((c.i >> 16) & 1u)) >> 16);
}
__device__ __forceinline__ float geluf(float v) {
  return 0.5f * v * (1.f + erff(v * 0.70710678118654752f));
}
__device__ __forceinline__ float softplusf(float v) {
  return (v > 0.f) ? (v + log1pf(__expf(-v))) : log1pf(__expf(v));
}
__device__ __forceinline__ float siluf(float v) {
  return v / (1.f + __expf(-v));
}
__device__ __forceinline__ float exp2_fast(float v) {
  return __builtin_amdgcn_exp2f(v);
}
// branch-free softplus: max(v,0) + ln(1 + e^{-|v|});  v_exp_f32 + v_log_f32.
__device__ __forceinline__ float softplus_fast(float v) {
  const float a = __builtin_fabsf(v);
  const float e = exp2_fast(-a * 1.44269504088896f);
  const float l = __log2f(1.f + e) * 0.69314718055995f;
  return fmaxf(v, 0.f) + l;
}

// async 16B global -> LDS (dest = wave-uniform lds base + lane*16)
__device__ __forceinline__ void async16(const u16* g, u16* l) {
  __builtin_amdgcn_global_load_lds(
      (const __attribute__((address_space(1))) uint*)g,
      (__attribute__((address_space(3))) uint*)l, 16, 0, 0);
}

// ---------------------------------------------------------------------------
// LayerNorm fp32 row (1024) -> bf16.  One block per row.
// ---------------------------------------------------------------------------
__global__ __launch_bounds__(256) void ln_kernel(
    const float* __restrict__ x, const float* __restrict__ g,
    const float* __restrict__ b, u16* __restrict__ out) {
  const int row = blockIdx.x;
  const int tid = threadIdx.x;
  const float4 v = ((const float4*)(x + (size_t)row * kD))[tid];
  float s  = v.x + v.y + v.z + v.w;
  float ss = v.x * v.x + v.y * v.y + v.z * v.z + v.w * v.w;
  #pragma unroll
  for (int off = 32; off; off >>= 1) {
    s  += __shfl_xor(s, off);
    ss += __shfl_xor(ss, off);
  }
  __shared__ float ls[4], lss[4];
  const int wid = tid >> 6;
  if ((tid & 63) == 0) { ls[wid] = s; lss[wid] = ss; }
  __syncthreads();
  s  = ls[0] + ls[1] + ls[2] + ls[3];
  ss = lss[0] + lss[1] + lss[2] + lss[3];
  const float mu  = s * (1.f / kD);
  const float inv = rsqrtf(ss * (1.f / kD) - mu * mu + 1e-5f);
  const float4 gg = ((const float4*)g)[tid];
  const float4 bb = ((const float4*)b)[tid];
  ushort4 o;
  o.x = f2bf((v.x - mu) * inv * gg.x + bb.x);
  o.y = f2bf((v.y - mu) * inv * gg.y + bb.y);
  o.z = f2bf((v.z - mu) * inv * gg.z + bb.z);
  o.w = f2bf((v.w - mu) * inv * gg.w + bb.w);
  ((ushort4*)(out + (size_t)row * kD))[tid] = o;
}

// combined: out = x + gelu(out + x); h = LN(out) bf16.  One block per row.
__global__ __launch_bounds__(256) void combine_ln_kernel(
    const float* __restrict__ x, float* __restrict__ out,
    const float* __restrict__ g, const float* __restrict__ b,
    u16* __restrict__ h) {
  const int row = blockIdx.x;
  const int tid = threadIdx.x;
  const float4 xv = ((const float4*)(x + (size_t)row * kD))[tid];
  const float4 bv = ((const float4*)(out + (size_t)row * kD))[tid];
  float4 o;
  o.x = xv.x + geluf(bv.x + xv.x);
  o.y = xv.y + geluf(bv.y + xv.y);
  o.z = xv.z + geluf(bv.z + xv.z);
  o.w = xv.w + geluf(bv.w + xv.w);
  ((float4*)(out + (size_t)row * kD))[tid] = o;
  float s  = o.x + o.y + o.z + o.w;
  float ss = o.x * o.x + o.y * o.y + o.z * o.z + o.w * o.w;
  #pragma unroll
  for (int off = 32; off; off >>= 1) {
    s  += __shfl_xor(s, off);
    ss += __shfl_xor(ss, off);
  }
  __shared__ float ls[4], lss[4];
  const int wid = tid >> 6;
  if ((tid & 63) == 0) { ls[wid] = s; lss[wid] = ss; }
  __syncthreads();
  s  = ls[0] + ls[1] + ls[2] + ls[3];
  ss = lss[0] + lss[1] + lss[2] + lss[3];
  const float mu  = s * (1.f / kD);
  const float inv = rsqrtf(ss * (1.f / kD) - mu * mu + 1e-5f);
  const float4 gg = ((const float4*)g)[tid];
  const float4 bb = ((const float4*)b)[tid];
  ushort4 ho;
  ho.x = f2bf((o.x - mu) * inv * gg.x + bb.x);
  ho.y = f2bf((o.y - mu) * inv * gg.y + bb.y);
  ho.z = f2bf((o.z - mu) * inv * gg.z + bb.z);
  ho.w = f2bf((o.w - mu) * inv * gg.w + bb.w);
  ((ushort4*)(h + (size_t)row * kD))[tid] = ho;
}

// ---------------------------------------------------------------------------
// Fused weight conversion: all fp32->bf16 weight jobs in one launch.
// ---------------------------------------------------------------------------
struct KJob { const float* s; u16* d; int n4; int blk0; int xp; };
struct KJobs { KJob j[10]; };

__global__ __launch_bounds__(256) void cvt_all_kernel(KJobs J) {
  const int bi = blockIdx.x;
  #pragma unroll
  for (int k = 0; k < 10; k++) {
    const KJob job = J.j[k];
    const int nb = (job.n4 + 255) >> 8;
    if (bi >= job.blk0 && bi < job.blk0 + nb) {
      const int i = (bi - job.blk0) * 256 + threadIdx.x;
      if (i < job.n4) {
        ushort4 o = {0, 0, 0, 0};
        bool valid = true;
        if (job.xp) valid = ((i * 4) >> 11) < (kDtRank + 2 * kDS);
        if (valid) {
          const float4 v = ((const float4*)job.s)[i];
          o.x = f2bf(v.x); o.y = f2bf(v.y); o.z = f2bf(v.z); o.w = f2bf(v.w);
        }
        ((ushort4*)job.d)[i] = o;
      }
      return;
    }
  }
}

// ---------------------------------------------------------------------------
// bf16 MFMA GEMM (2-phase): TILEN=128 (4 waves 2x2, 64x64/wave) or
// TILEN=64 (4 waves 4x1, 32x64/wave; for N=1024 GEMMs).
// XSWZ: bijective XCD-aware block swizzle (requires nwg % 8 == 0).
// ---------------------------------------------------------------------------
template <int TILEN, int ACT, bool BIAS, bool ACC, bool OUTBF, bool REV,
          bool AMAP, bool CMAP, bool XSWZ>
__global__ __launch_bounds__(256) void gemm_mfma(
    const u16* __restrict__ A, int lda,
    const u16* __restrict__ W, int ldw,
    void* __restrict__ Cp, int ldc, int K,
    const float* __restrict__ bias, int seg_len, int row_off) {
  constexpr int MI = (TILEN == 128) ? 4 : 2;     // M-frags per wave
  constexpr int WSTR = TILEN / 32;               // W staging strips
  __shared__ __align__(16) u16 As[128][64];
  __shared__ __align__(16) u16 Ws[TILEN][64];
  const int tid  = threadIdx.x;
  int bx = blockIdx.x, by = blockIdx.y;
  if (XSWZ) {
    const int nbx = gridDim.x;
    const int nwg = nbx * gridDim.y;
    const int bid = by * nbx + bx;
    const int sbid = (bid & 7) * (nwg >> 3) + (bid >> 3);
    bx = sbid % nbx;
    by = sbid / nbx;
  }
  const int bm   = bx * 128;
  const int bn   = by * TILEN;
  const int lane = tid & 63;
  const int wv   = tid >> 6;
  const int wm   = (TILEN == 128) ? (wv >> 1) * 64 : wv * 32;
  const int wn   = (TILEN == 128) ? (wv & 1) * 64 : 0;
  const int l15  = lane & 15;
  const int quad = lane >> 4;
  const int srow = lane >> 3;
  const int swz  = ((lane & 7) ^ srow) * 8;
  const int jx   = (l15 & 7) * 16;

  int ab = 0, all0 = bm;
  if (AMAP || CMAP) {
    ab = bm / seg_len;
    all0 = bm - ab * seg_len;
  }

  int arowv[4];
  #pragma unroll
  for (int it = 0; it < 4; it++) {
    const int rl = it * 32 + wv * 8 + srow;
    if (AMAP) {
      arowv[it] = REV ? (ab * kL + kL - 1 - row_off - all0 - rl)
                      : (ab * kL + row_off + all0 + rl);
    } else {
      arowv[it] = bm + rl;
    }
  }

  f32x4 acc[MI][4];
  #pragma unroll
  for (int i = 0; i < MI; i++)
    #pragma unroll
    for (int j = 0; j < 4; j++) acc[i][j] = (f32x4){0.f, 0.f, 0.f, 0.f};

  for (int k0 = 0; k0 < K; k0 += 64) {
    #pragma unroll
    for (int it = 0; it < 4; it++) {
      const int rl = it * 32 + wv * 8 + srow;
      async16(A + (size_t)arowv[it] * lda + k0 + swz, &As[it * 32 + wv * 8][0]);
    }
    #pragma unroll
    for (int it = 0; it < WSTR; it++) {
      const int rl = it * 32 + wv * 8 + srow;
      async16(W + (size_t)(bn + rl) * ldw + k0 + swz, &Ws[it * 32 + wv * 8][0]);
    }
    __syncthreads();
    #pragma unroll
    for (int ks = 0; ks < 64; ks += 32) {
      const int cb = ((ks >> 3) + quad) * 16;
      bf16x8 af[MI], wf[4];
      #pragma unroll
      for (int i = 0; i < MI; i++)
        af[i] = *(const bf16x8*)((const char*)&As[wm + i * 16 + l15][0] +
                                 (cb ^ jx));
      #pragma unroll
      for (int j = 0; j < 4; j++)
        wf[j] = *(const bf16x8*)((const char*)&Ws[wn + j * 16 + l15][0] +
                                 (cb ^ jx));
      #pragma unroll
      for (int i = 0; i < MI; i++)
        #pragma unroll
        for (int j = 0; j < 4; j++)
          acc[i][j] = __builtin_amdgcn_mfma_f32_16x16x32_bf16(
              af[i], wf[j], acc[i][j], 0, 0, 0);
    }
    __syncthreads();
  }

  #pragma unroll
  for (int i = 0; i < MI; i++) {
    #pragma unroll
    for (int j = 0; j < 4; j++) {
      const int col = bn + wn + j * 16 + l15;
      #pragma unroll
      for (int r = 0; r < 4; r++) {
        const int rl2 = wm + i * 16 + quad * 4 + r;
        const int crow = CMAP ? (ab * kL + row_off + all0 + rl2) : (bm + rl2);
        float v = acc[i][j][r];
        if (BIAS) v += bias[col];
        if (ACT == 1) v = softplusf(v);
        if (ACT == 2) v = geluf(v);
        if (OUTBF) {
          ((u16*)Cp)[(size_t)crow * ldc + col] = f2bf(v);
        } else {
          float* p = (float*)Cp + (size_t)crow * ldc + col;
          if (ACC) *p = *p + v; else *p = v;
        }
      }
    }
  }
}

// ---------------------------------------------------------------------------
// x_proj split-K: dblp[kq] = xs[bm:bm+128, kq*256:(kq+1)*256] @ W^T partial.
// Grid (Mseg/128, 8).  Same 2-phase body; f32 partial output.
// ---------------------------------------------------------------------------
__global__ __launch_bounds__(256) void xproj_k8_kernel(
    const u16* __restrict__ A, const u16* __restrict__ W,
    float* __restrict__ xpp, int Mrows) {
  __shared__ __align__(16) u16 As[128][64];
  __shared__ __align__(16) u16 Ws[128][64];
  const int tid  = threadIdx.x;
  const int bm   = blockIdx.x * 128;
  const int kq   = blockIdx.y;          // 0..7 K-chunk
  const int lane = tid & 63;
  const int wv   = tid >> 6;
  const int wm   = (wv >> 1) * 64;
  const int wn   = (wv & 1) * 64;
  const int l15  = lane & 15;
  const int quad = lane >> 4;
  const int srow = lane >> 3;
  const int swz  = ((lane & 7) ^ srow) * 8;
  const int jx   = (l15 & 7) * 16;

  f32x4 acc[4][4];
  #pragma unroll
  for (int i = 0; i < 4; i++)
    #pragma unroll
    for (int j = 0; j < 4; j++) acc[i][j] = (f32x4){0.f, 0.f, 0.f, 0.f};

  const int kbeg = kq * 256;
  for (int k0 = kbeg; k0 < kbeg + 256; k0 += 64) {
    #pragma unroll
    for (int it = 0; it < 4; it++) {
      const int rl = it * 32 + wv * 8 + srow;
      async16(A + (size_t)(bm + rl) * kDI + k0 + swz, &As[it * 32 + wv * 8][0]);
      async16(W + (size_t)rl * kDI + k0 + swz, &Ws[it * 32 + wv * 8][0]);
    }
    __syncthreads();
    #pragma unroll
    for (int ks = 0; ks < 64; ks += 32) {
      const int cb = ((ks >> 3) + quad) * 16;
      bf16x8 af[4], wf[4];
      #pragma unroll
      for (int i = 0; i < 4; i++)
        af[i] = *(const bf16x8*)((const char*)&As[wm + i * 16 + l15][0] +
                                 (cb ^ jx));
      #pragma unroll
      for (int j = 0; j < 4; j++)
        wf[j] = *(const bf16x8*)((const char*)&Ws[wn + j * 16 + l15][0] +
                                 (cb ^ jx));
      #pragma unroll
      for (int i = 0; i < 4; i++)
        #pragma unroll
        for (int j = 0; j < 4; j++)
          acc[i][j] = __builtin_amdgcn_mfma_f32_16x16x32_bf16(
              af[i], wf[j], acc[i][j], 0, 0, 0);
    }
    __syncthreads();
  }

  float* outp = xpp + (size_t)kq * Mrows * kNPad;
  #pragma unroll
  for (int i = 0; i < 4; i++) {
    #pragma unroll
    for (int j = 0; j < 4; j++) {
      const int col = wn + j * 16 + l15;
      #pragma unroll
      for (int r = 0; r < 4; r++) {
        const int row = bm + wm + i * 16 + quad * 4 + r;
        outp[(size_t)row * kNPad + col] = acc[i][j][r];
      }
    }
  }
}

// reduce 8 f32 partials -> bf16 dbl
__global__ __launch_bounds__(256) void xproj_reduce_kernel(
    const float* __restrict__ xpp, u16* __restrict__ dbl, int n) {
  const int i = blockIdx.x * 256 + threadIdx.x;
  float s = 0.f;
  #pragma unroll
  for (int k = 0; k < 8; k++) s += xpp[(size_t)k * n + i];
  dbl[i] = f2bf(s);
}

// ---------------------------------------------------------------------------
// Dedicated dt_proj kernel: dtb = softplus(dbl[:, :64] @ dt_w^T + dt_b).
// ---------------------------------------------------------------------------
__global__ __launch_bounds__(256) void dt_kernel(
    const u16* __restrict__ dbl, const u16* __restrict__ wdt,
    const float* __restrict__ bias, u16* __restrict__ dtb) {
  __shared__ __align__(16) u16 sh[2][128][64];   // stage A/W; then C[128][128]
  const int tid  = threadIdx.x;
  const int bm   = blockIdx.x * 128;
  const int bn   = blockIdx.y * 128;
  const int lane = tid & 63;
  const int wv   = tid >> 6;
  const int wm   = (wv >> 1) * 64;
  const int wn   = (wv & 1) * 64;
  const int l15  = lane & 15;
  const int quad = lane >> 4;
  const int srow = lane >> 3;
  const int swz  = ((lane & 7) ^ srow) * 8;
  const int jx   = (l15 & 7) * 16;

  #pragma unroll
  for (int it = 0; it < 4; it++) {
    const int rl = it * 32 + wv * 8 + srow;
    async16(dbl + (size_t)(bm + rl) * kNPad + swz, &sh[0][it * 32 + wv * 8][0]);
    async16(wdt + (size_t)(bn + rl) * kDtRank + swz,
            &sh[1][it * 32 + wv * 8][0]);
  }
  __syncthreads();

  f32x4 acc[4][4];
  #pragma unroll
  for (int i = 0; i < 4; i++)
    #pragma unroll
    for (int j = 0; j < 4; j++) acc[i][j] = (f32x4){0.f, 0.f, 0.f, 0.f};

  #pragma unroll
  for (int ks = 0; ks < 2; ks++) {
    const int cb = (ks * 4 + quad) * 16;
    bf16x8 af[4], wf[4];
    #pragma unroll
    for (int i = 0; i < 4; i++)
      af[i] = *(const bf16x8*)((const char*)&sh[0][wm + i * 16 + l15][0] +
                               (cb ^ jx));
    #pragma unroll
    for (int j = 0; j < 4; j++)
      wf[j] = *(const bf16x8*)((const char*)&sh[1][wn + j * 16 + l15][0] +
                               (cb ^ jx));
    #pragma unroll
    for (int i = 0; i < 4; i++)
      #pragma unroll
      for (int j = 0; j < 4; j++)
        acc[i][j] = __builtin_amdgcn_mfma_f32_16x16x32_bf16(
            af[i], wf[j], acc[i][j], 0, 0, 0);
  }
  __syncthreads();   // all waves done reading staging LDS

  u16* C = &sh[0][0][0];   // alias as [128][128] u16 tile (exactly 32KB)
  #pragma unroll
  for (int i = 0; i < 4; i++) {
    #pragma unroll
    for (int j = 0; j < 4; j++) {
      const int colL = wn + j * 16 + l15;
      const float bv = bias[bn + colL];
      #pragma unroll
      for (int r = 0; r < 4; r++) {
        const int rl2 = wm + i * 16 + quad * 4 + r;
        C[rl2 * 128 + colL] = f2bf(softplus_fast(acc[i][j][r] + bv));
      }
    }
  }
  __syncthreads();

  #pragma unroll
  for (int i = 0; i < 8; i++) {
    const int cidx = i * 256 + tid;        // ushort8 chunk id, 2048 total
    const int row  = cidx >> 4;
    const int cin  = (cidx & 15) * 8;
    const ushort8 val = *(const ushort8*)&C[row * 128 + cin];
    *(ushort8*)&dtb[(size_t)(bm + row) * kDI + bn + cin] = val;
  }
}

// ---------------------------------------------------------------------------
// Causal depthwise conv (k=4) + bias + silu on one segment (compact rows).
// ---------------------------------------------------------------------------
__global__ __launch_bounds__(256) void conv_silu_kernel(
    const u16* __restrict__ xz, const float* __restrict__ w,
    const float* __restrict__ cb, u16* __restrict__ xs,
    const u16* __restrict__ tail_in, u16* __restrict__ tail_out,
    int seg_len, int row_off) {
  const int t = blockIdx.x * 256 + threadIdx.x;  // Mseg*kDI threads
  const int c = t & (kDI - 1);
  const int r = t >> 11;              // compact row
  const int b = r / seg_len;
  const int ll = r - b * seg_len;
  const int tpos = row_off + ll;      // processing-order position in [0,L)

  const float xv0 = bf2f(xz[(size_t)r * (2 * kDI) + c]);
  float acc = cb[c] + w[c * 4 + 3] * xv0;
  #pragma unroll
  for (int j = 1; j <= 3; j++) {
    if (tpos - j >= 0) {
      float xp;
      if (ll - j >= 0) {
        xp = bf2f(xz[(size_t)(r - j) * (2 * kDI) + c]);
      } else {
        xp = bf2f(tail_in[(b * 3 + (3 + ll - j)) * kDI + c]);
      }
      acc += w[c * 4 + 3 - j] * xp;
    }
  }
  xs[(size_t)r * kDI + c] = f2bf(siluf(acc));
  if (ll >= seg_len - 3) {
    tail_out[(b * 3 + (ll - (seg_len - 3))) * kDI + c] = f2bf(xv0);
  }
}

// ---------------------------------------------------------------------------
// Scan phase A: per (b, c, chunk), 16 states in registers, no cross-lane.
// ---------------------------------------------------------------------------
__global__ __launch_bounds__(256, 8) void scan_phaseA(
    const u16* __restrict__ dt, const u16* __restrict__ xs,
    const u16* __restrict__ dbl, const float* __restrict__ Alog,
    float* __restrict__ Pbuf, float* __restrict__ Hbuf,
    int Lseg, int Lc) {
  __shared__ float Bls[32][16];
  const int tid = threadIdx.x;
  const int c = blockIdx.x * 256 + tid;
  const int k = blockIdx.y;
  const int b = blockIdx.z;
  const int base = b * Lseg + k * Lc;
  for (int idx = tid; idx < Lc * 16; idx += 256) {
    const int r = idx >> 4, j = idx & 15;
    Bls[r][j] = bf2f(dbl[(size_t)(base + r) * kNPad + kDtRank + j]);
  }
  __syncthreads();
  float Ac[16], h[16];
  float dtsum = 0.f;
  #pragma unroll
  for (int s = 0; s < 16; s++) {
    Ac[s] = -__expf(Alog[c * kDS + s]) * 1.44269504088896f;  // *log2(e)
    h[s] = 0.f;
  }
  for (int r = 0; r < Lc; r++) {
    const size_t row = (size_t)(base + r);
    const float dtv = bf2f(dt[row * kDI + c]);
    const float dtx = dtv * bf2f(xs[row * kDI + c]);
    dtsum += dtv;
    const float4* Brow = (const float4*)Bls[r];
    #pragma unroll
    for (int s4 = 0; s4 < 4; s4++) {
      const float4 Bv = Brow[s4];
      const float bb[4] = {Bv.x, Bv.y, Bv.z, Bv.w};
      #pragma unroll
      for (int q = 0; q < 4; q++) {
        const int s = s4 * 4 + q;
        const float dA = exp2_fast(dtv * Ac[s]);
        h[s] = dA * h[s] + dtx * bb[q];
      }
    }
  }
  const size_t o = (((size_t)b * kNCH + k) * kDI + c) * 16;
  #pragma unroll
  for (int s4 = 0; s4 < 4; s4++) {
    *(float4*)&Pbuf[o + s4 * 4] =
        make_float4(exp2_fast(Ac[s4 * 4 + 0] * dtsum),
                    exp2_fast(Ac[s4 * 4 + 1] * dtsum),
                    exp2_fast(Ac[s4 * 4 + 2] * dtsum),
                    exp2_fast(Ac[s4 * 4 + 3] * dtsum));
    *(float4*)&Hbuf[o + s4 * 4] =
        make_float4(h[s4 * 4], h[s4 * 4 + 1], h[s4 * 4 + 2], h[s4 * 4 + 3]);
  }
}

// ---------------------------------------------------------------------------
// Scan phase B: stitch chunks; h_in per chunk written over Pbuf.
// ---------------------------------------------------------------------------
__global__ __launch_bounds__(256) void scan_phaseB(
    float* __restrict__ Pbuf, const float* __restrict__ Hbuf,
    float* __restrict__ hstate, int first) {
  const int t = blockIdx.x * 256 + threadIdx.x;  // B*di*16
  const int s = t & 15;
  const int c = (t >> 4) & (kDI - 1);
  const int b = t >> 15;
  float cur = first ? 0.f : hstate[t];
  for (int k = 0; k < kNCH; k++) {
    const size_t idx = (((size_t)b * kNCH + k) * kDI + c) * 16 + s;
    const float p = Pbuf[idx];
    const float hl = Hbuf[idx];
    Pbuf[idx] = cur;
    cur = p * cur + hl;
  }
  hstate[t] = cur;
}

// ---------------------------------------------------------------------------
// Scan phase C: re-run chunk with true h_in, y = C.h + D*x, *silu(z) -> xs.
// ---------------------------------------------------------------------------
__global__ __launch_bounds__(256, 8) void scan_phaseC(
    const u16* __restrict__ dt, u16* __restrict__ xs,
    const u16* __restrict__ dbl, const u16* __restrict__ xz,
    const float* __restrict__ Alog, const float* __restrict__ Dp,
    const float* __restrict__ Pbuf, int Lseg, int Lc) {
  __shared__ float BC[32][32];  // [r][0:16]=B, [r][16:32]=C
  const int tid = threadIdx.x;
  const int c = blockIdx.x * 256 + tid;
  const int k = blockIdx.y;
  const int b = blockIdx.z;
  const int base = b * Lseg + k * Lc;
  for (int idx = tid; idx < Lc * 32; idx += 256) {
    const int r = idx >> 5, j = idx & 31;
    BC[r][j] = bf2f(dbl[(size_t)(base + r) * kNPad + kDtRank + j]);
  }
  __syncthreads();
  float Ac[16], h[16];
  const size_t o = (((size_t)b * kNCH + k) * kDI + c) * 16;
  #pragma unroll
  for (int s4 = 0; s4 < 4; s4++) {
    const float4 hv = *(const float4*)&Pbuf[o + s4 * 4];
    h[s4 * 4 + 0] = hv.x; h[s4 * 4 + 1] = hv.y;
    h[s4 * 4 + 2] = hv.z; h[s4 * 4 + 3] = hv.w;
  }
  #pragma unroll
  for (int s = 0; s < 16; s++)
    Ac[s] = -__expf(Alog[c * kDS + s]) * 1.44269504088896f;  // *log2(e)
  const float Dv = Dp[c];
  for (int r = 0; r < Lc; r++) {
    const size_t row = (size_t)(base + r);
    const float dtv = bf2f(dt[row * kDI + c]);
    const float xv = bf2f(xs[row * kDI + c]);
    const float dtx = dtv * xv;
    float y = 0.f;
    const float4* Brow = (const float4*)BC[r];
    const float4* Crow = (const float4*)&BC[r][16];
    #pragma unroll
    for (int s4 = 0; s4 < 4; s4++) {
      const float4 Bv = Brow[s4];
      const float4 Cv = Crow[s4];
      const float bb[4] = {Bv.x, Bv.y, Bv.z, Bv.w};
      const float cc[4] = {Cv.x, Cv.y, Cv.z, Cv.w};
      #pragma unroll
      for (int q = 0; q < 4; q++) {
        const int s = s4 * 4 + q;
        const float dA = exp2_fast(dtv * Ac[s]);
        h[s] = dA * h[s] + dtx * bb[q];
        y += h[s] * cc[q];
      }
    }
    const float z = bf2f(xz[row * (2 * kDI) + kDI + c]);
    xs[row * kDI + c] = f2bf((y + Dv * xv) * siluf(z));
  }
}

}  // namespace

extern "C" void kernel_launch(void* const* d_in, const int* in_sizes, int n_in,
                              void* d_out, int out_size, void* d_ws,
                              size_t ws_size, hipStream_t stream) {
  const float* x = (const float*)d_in[0];
  const float* in_w[2]    = {(const float*)d_in[1],  (const float*)d_in[10]};
  const float* conv_w[2]  = {(const float*)d_in[2],  (const float*)d_in[11]};
  const float* conv_b[2]  = {(const float*)d_in[3],  (const float*)d_in[12]};
  const float* xproj_w[2] = {(const float*)d_in[4],  (const float*)d_in[13]};
  const float* dt_w[2]    = {(const float*)d_in[5],  (const float*)d_in[14]};
  const float* dt_b[2]    = {(const float*)d_in[6],  (const float*)d_in[15]};
  const float* Alog[2]    = {(const float*)d_in[7],  (const float*)d_in[16]};
  const float* Dp[2]      = {(const float*)d_in[8],  (const float*)d_in[17]};
  const float* out_w[2]   = {(const float*)d_in[9],  (const float*)d_in[18]};
  const float* norm_g = (const float*)d_in[19];
  const float* norm_b = (const float*)d_in[20];
  const float* ffn_g  = (const float*)d_in[21];
  const float* ffn_b  = (const float*)d_in[22];
  const float* ff1_w  = (const float*)d_in[23];
  const float* ff1_b  = (const float*)d_in[24];
  const float* ff2_w  = (const float*)d_in[25];
  const float* ff2_b  = (const float*)d_in[26];
  float* out = (float*)d_out;

  // --- adaptive workspace layout ---------------------------------------
  constexpr size_t kWCache =
      2 * ((size_t)4096 * kD + (size_t)kD * kDI + (size_t)kNPad * kDI +
           (size_t)kDI * kDtRank) * 2 +
      ((size_t)kDFF * kD + (size_t)kD * kDFF) * 2;  // bf16 weights
  auto need = [](int nseg) -> size_t {
    const size_t mseg = (size_t)kM / nseg;
    size_t sz = kWCache + 4096;
    sz += (size_t)kM * kD * 2;            // h bf16
    sz += mseg * 4096 * 2;                // xz bf16 (aliases FFN hidden)
    sz += mseg * 2048 * 2;                // xs bf16
    sz += mseg * 128 * 2;                 // dbl bf16
    sz += mseg * 2048 * 2;                // dt bf16
    sz += 8 * mseg * 128 * 4;             // x_proj split-K partials (f32)
    sz += 2 * (size_t)kB * kNCH * kDI * kDS * 4;  // Pbuf + Hbuf
    sz += (size_t)kB * kDI * kDS * 4;     // hstate
    sz += 2 * (size_t)kB * 3 * kDI * 2;   // conv tails
    sz += 32 * 256;                       // alignment slack
    return sz;
  };
  int nseg = 1;
  while (nseg <= 16 && need(nseg) > ws_size) nseg *= 2;
  if (nseg > 16) return;  // clean fail
  const int Lseg = kL / nseg;
  const int Mseg = kM / nseg;
  const int Lc = Lseg / kNCH;

  char* base = (char*)d_ws;
  size_t off = 0;
  auto alloc = [&](size_t bytes) {
    char* p = base + off;
    off = (off + bytes + 255) & ~(size_t)255;
    return p;
  };
  // bf16 weight cache
  u16* w_in[2], *w_out[2], *w_xp[2], *w_dt[2];
  for (int m = 0; m < 2; m++) {
    w_in[m]  = (u16*)alloc((size_t)4096 * kD * 2);
    w_out[m] = (u16*)alloc((size_t)kD * kDI * 2);
    w_xp[m]  = (u16*)alloc((size_t)kNPad * kDI * 2);
    w_dt[m]  = (u16*)alloc((size_t)kDI * kDtRank * 2);
  }
  u16* w_f1 = (u16*)alloc((size_t)kDFF * kD * 2);
  u16* w_f2 = (u16*)alloc((size_t)kD * kDFF * 2);
  // activations
  u16*   h      = (u16*)alloc((size_t)kM * kD * 2);
  u16*   xz     = (u16*)alloc((size_t)Mseg * 4096 * 2);
  u16*   xs     = (u16*)alloc((size_t)Mseg * 2048 * 2);
  u16*   dbl    = (u16*)alloc((size_t)Mseg * 128 * 2);
  u16*   dtb    = (u16*)alloc((size_t)Mseg * 2048 * 2);
  float* xpp    = (float*)alloc((size_t)8 * Mseg * 128 * 4);
  float* Pbuf   = (float*)alloc((size_t)kB * kNCH * kDI * kDS * 4);
  float* Hbuf   = (float*)alloc((size_t)kB * kNCH * kDI * kDS * 4);
  float* hstate = (float*)alloc((size_t)kB * kDI * kDS * 4);
  u16*   tail0  = (u16*)alloc((size_t)kB * 3 * kDI * 2);
  u16*   tail1  = (u16*)alloc((size_t)kB * 3 * kDI * 2);

  // fused weight conversion (once per call)
  {
    KJobs J;
    int b = 0, ji = 0;
    auto addjob = [&](const float* s, u16* d, int n4, int xp) {
      J.j[ji].s = s; J.j[ji].d = d; J.j[ji].n4 = n4;
      J.j[ji].blk0 = b; J.j[ji].xp = xp;
      b += (n4 + 255) >> 8;
      ji++;
    };
    for (int m = 0; m < 2; m++) {
      addjob(in_w[m],  w_in[m],  (4096 * kD) / 4, 0);
      addjob(out_w[m], w_out[m], (kD * kDI) / 4, 0);
      addjob(xproj_w[m], w_xp[m], (kNPad * kDI) / 4, 1);
      addjob(dt_w[m],  w_dt[m],  (kDI * kDtRank) / 4, 0);
    }
    addjob(ff1_w, w_f1, (kDFF * kD) / 4, 0);
    addjob(ff2_w, w_f2, (kD * kDFF) / 4, 0);
    cvt_all_kernel<<<b, 256, 0, stream>>>(J);
  }

  // LN(x) -> h (bf16)
  ln_kernel<<<kM, 256, 0, stream>>>(x, norm_g, norm_b, h);

  for (int m = 0; m < 2; m++) {
    for (int s = 0; s < nseg; s++) {
      const int l0 = s * Lseg;
      u16* tin  = (s & 1) ? tail0 : tail1;
      u16* tout = (s & 1) ? tail1 : tail0;
      // in_proj: h rows (REV for m=1) x in_w[4096,1024]^T -> xz [Mseg,4096]
      if (m == 0)
        gemm_mfma<128, 0, false, false, true, false, true, false, true>
            <<<dim3(Mseg / 128, 4096 / 128), 256, 0, stream>>>(
                h, kD, w_in[m], kD, xz, 4096, kD, nullptr, Lseg, l0);
      else
        gemm_mfma<128, 0, false, false, true, true, true, false, true>
            <<<dim3(Mseg / 128, 4096 / 128), 256, 0, stream>>>(
                h, kD, w_in[m], kD, xz, 4096, kD, nullptr, Lseg, l0);
      // causal depthwise conv + silu -> xs
      conv_silu_kernel<<<(Mseg * kDI) / 256, 256, 0, stream>>>(
          xz, conv_w[m], conv_b[m], xs, tin, tout, Lseg, l0);
      // x_proj: split-K x8 -> f32 partials -> reduce to bf16 dbl
      xproj_k8_kernel<<<dim3(Mseg / 128, 8), 256, 0, stream>>>(
          xs, w_xp[m], xpp, Mseg);
      xproj_reduce_kernel<<<(Mseg * kNPad) / 256, 256, 0, stream>>>(
          xpp, dbl, Mseg * kNPad);
      // dt_proj + softplus: dedicated kernel
      dt_kernel<<<dim3(Mseg / 128, kDI / 128), 256, 0, stream>>>(
          dbl, w_dt[m], dt_b[m], dtb);
      // chunked scan: A (local), B (stitch), C (emit y into xs)
      scan_phaseA<<<dim3(kDI / 256, kNCH, kB), 256, 0, stream>>>(
          dtb, xs, dbl, Alog[m], Pbuf, Hbuf, Lseg, Lc);
      scan_phaseB<<<(kB * kDI * kDS) / 256, 256, 0, stream>>>(
          Pbuf, Hbuf, hstate, (s == 0) ? 1 : 0);
      scan_phaseC<<<dim3(kDI / 256, kNCH, kB), 256, 0, stream>>>(
          dtb, xs, dbl, xz, Alog[m], Dp[m], Pbuf, Lseg, Lc);
      // out_proj -> d_out rows (f32); m=1 accumulates (TILEN=64 2-phase)
      if (m == 0)
        gemm_mfma<64, 0, false, false, false, false, false, true, true>
            <<<dim3(Mseg / 128, kD / 64), 256, 0, stream>>>(
                xs, kDI, w_out[m], kDI, out, kD, kDI, nullptr, Lseg, l0);
      else
        gemm_mfma<64, 0, false, true, false, false, false, true, true>
            <<<dim3(Mseg / 128, kD / 64), 256, 0, stream>>>(
                xs, kDI, w_out[m], kDI, out, kD, kDI, nullptr, Lseg, l0);
    }
  }

  // x2 = x + gelu(fwd + bwd + x) in place on d_out; h = LN(x2) (fused)
  combine_ln_kernel<<<kM, 256, 0, stream>>>(x, out, ffn_g, ffn_b, h);

  // FFN: per M-segment: hidden = gelu(h@ff1^T+b1) (alias xz);
  // out += hidden@ff2^T + b2
  for (int s = 0; s < nseg; s++) {
    const int r0 = s * Mseg;
    gemm_mfma<128, 2, true, false, true, false, true, false, true>
        <<<dim3(Mseg / 128, kDFF / 128), 256, 0, stream>>>(
            h, kD, w_f1, kD, xz, kDFF, kD, ff1_b, Mseg, r0);
    gemm_mfma<64, 0, true, true, false, false, false, true, true>
        <<<dim3(Mseg / 128, kD / 64), 256, 0, stream>>>(
            xz, kDFF, w_f2, kDFF, out, kD, kDFF, ff2_b, Mseg, r0);
  }
}

// Round 9
// 1441.440 us; speedup vs baseline: 1.0601x; 1.0601x over previous
//
#include <hip/hip_runtime.h>
#include <cmath>

// ---------------------------------------------------------------------------
// BiDirectionalAddFFBlock: LN -> mamba(fwd)+mamba(rev) -> gelu residual ->
// LN -> FFN.  B=4, L=2048, D=1024, di=2048, ds=16, dt_rank=64, DFF=4096.
// Round 15: R14 hit "container failed twice" (infra flake, same signature
// as R11; all code paths in this source already passed on HW in R7/R12).
// Resubmitting unchanged for a clean measurement.
// R14: XSWZ reverted everywhere (R13's chunked XCD remap broke the natural
// bx-stripe L2 locality: out_proj FETCH 33.5->69.9MB, MfmaUtil 24->11.6%).
// Split-K x8 x_proj kept (0.25 -> 2 blocks/CU; mechanism sound, separable).
// ---------------------------------------------------------------------------

namespace {

using u16 = unsigned short;
using uint = unsigned int;

constexpr int kB = 4;
constexpr int kL = 2048;
constexpr int kD = 1024;
constexpr int kDI = 2048;
constexpr int kDFF = 4096;
constexpr int kDS = 16;
constexpr int kDtRank = 64;
constexpr int kNPad = 128;       // x_proj N=96 padded to 128
constexpr int kM = kB * kL;      // 8192 rows
constexpr int kNCH = 64;         // scan chunks per segment

typedef short bf16x8 __attribute__((ext_vector_type(8)));
typedef float f32x4  __attribute__((ext_vector_type(4)));
typedef unsigned short ushort8 __attribute__((ext_vector_type(8)));

__device__ __forceinline__ float bf2f(u16 u) {
  union { unsigned int i; float f; } c; c.i = ((unsigned int)u) << 16; return c.f;
}
__device__ __forceinline__ u16 f2bf(float f) {  // round-to-nearest-even
  union { float f; unsigned int i; } c; c.f = f;
  return (u16)((c.i + 0x7FFFu + ((c.i >> 16) & 1u)) >> 16);
}
__device__ __forceinline__ float geluf(float v) {
  return 0.5f * v * (1.f + erff(v * 0.70710678118654752f));
}
__device__ __forceinline__ float softplusf(float v) {
  return (v > 0.f) ? (v + log1pf(__expf(-v))) : log1pf(__expf(v));
}
__device__ __forceinline__ float siluf(float v) {
  return v / (1.f + __expf(-v));
}
__device__ __forceinline__ float exp2_fast(float v) {
  return __builtin_amdgcn_exp2f(v);
}
// branch-free softplus: max(v,0) + ln(1 + e^{-|v|});  v_exp_f32 + v_log_f32.
__device__ __forceinline__ float softplus_fast(float v) {
  const float a = __builtin_fabsf(v);
  const float e = exp2_fast(-a * 1.44269504088896f);
  const float l = __log2f(1.f + e) * 0.69314718055995f;
  return fmaxf(v, 0.f) + l;
}

// async 16B global -> LDS (dest = wave-uniform lds base + lane*16)
__device__ __forceinline__ void async16(const u16* g, u16* l) {
  __builtin_amdgcn_global_load_lds(
      (const __attribute__((address_space(1))) uint*)g,
      (__attribute__((address_space(3))) uint*)l, 16, 0, 0);
}

// ---------------------------------------------------------------------------
// LayerNorm fp32 row (1024) -> bf16.  One block per row.
// ---------------------------------------------------------------------------
__global__ __launch_bounds__(256) void ln_kernel(
    const float* __restrict__ x, const float* __restrict__ g,
    const float* __restrict__ b, u16* __restrict__ out) {
  const int row = blockIdx.x;
  const int tid = threadIdx.x;
  const float4 v = ((const float4*)(x + (size_t)row * kD))[tid];
  float s  = v.x + v.y + v.z + v.w;
  float ss = v.x * v.x + v.y * v.y + v.z * v.z + v.w * v.w;
  #pragma unroll
  for (int off = 32; off; off >>= 1) {
    s  += __shfl_xor(s, off);
    ss += __shfl_xor(ss, off);
  }
  __shared__ float ls[4], lss[4];
  const int wid = tid >> 6;
  if ((tid & 63) == 0) { ls[wid] = s; lss[wid] = ss; }
  __syncthreads();
  s  = ls[0] + ls[1] + ls[2] + ls[3];
  ss = lss[0] + lss[1] + lss[2] + lss[3];
  const float mu  = s * (1.f / kD);
  const float inv = rsqrtf(ss * (1.f / kD) - mu * mu + 1e-5f);
  const float4 gg = ((const float4*)g)[tid];
  const float4 bb = ((const float4*)b)[tid];
  ushort4 o;
  o.x = f2bf((v.x - mu) * inv * gg.x + bb.x);
  o.y = f2bf((v.y - mu) * inv * gg.y + bb.y);
  o.z = f2bf((v.z - mu) * inv * gg.z + bb.z);
  o.w = f2bf((v.w - mu) * inv * gg.w + bb.w);
  ((ushort4*)(out + (size_t)row * kD))[tid] = o;
}

// combined: out = x + gelu(out + x); h = LN(out) bf16.  One block per row.
__global__ __launch_bounds__(256) void combine_ln_kernel(
    const float* __restrict__ x, float* __restrict__ out,
    const float* __restrict__ g, const float* __restrict__ b,
    u16* __restrict__ h) {
  const int row = blockIdx.x;
  const int tid = threadIdx.x;
  const float4 xv = ((const float4*)(x + (size_t)row * kD))[tid];
  const float4 bv = ((const float4*)(out + (size_t)row * kD))[tid];
  float4 o;
  o.x = xv.x + geluf(bv.x + xv.x);
  o.y = xv.y + geluf(bv.y + xv.y);
  o.z = xv.z + geluf(bv.z + xv.z);
  o.w = xv.w + geluf(bv.w + xv.w);
  ((float4*)(out + (size_t)row * kD))[tid] = o;
  float s  = o.x + o.y + o.z + o.w;
  float ss = o.x * o.x + o.y * o.y + o.z * o.z + o.w * o.w;
  #pragma unroll
  for (int off = 32; off; off >>= 1) {
    s  += __shfl_xor(s, off);
    ss += __shfl_xor(ss, off);
  }
  __shared__ float ls[4], lss[4];
  const int wid = tid >> 6;
  if ((tid & 63) == 0) { ls[wid] = s; lss[wid] = ss; }
  __syncthreads();
  s  = ls[0] + ls[1] + ls[2] + ls[3];
  ss = lss[0] + lss[1] + lss[2] + lss[3];
  const float mu  = s * (1.f / kD);
  const float inv = rsqrtf(ss * (1.f / kD) - mu * mu + 1e-5f);
  const float4 gg = ((const float4*)g)[tid];
  const float4 bb = ((const float4*)b)[tid];
  ushort4 ho;
  ho.x = f2bf((o.x - mu) * inv * gg.x + bb.x);
  ho.y = f2bf((o.y - mu) * inv * gg.y + bb.y);
  ho.z = f2bf((o.z - mu) * inv * gg.z + bb.z);
  ho.w = f2bf((o.w - mu) * inv * gg.w + bb.w);
  ((ushort4*)(h + (size_t)row * kD))[tid] = ho;
}

// ---------------------------------------------------------------------------
// Fused weight conversion: all fp32->bf16 weight jobs in one launch.
// ---------------------------------------------------------------------------
struct KJob { const float* s; u16* d; int n4; int blk0; int xp; };
struct KJobs { KJob j[10]; };

__global__ __launch_bounds__(256) void cvt_all_kernel(KJobs J) {
  const int bi = blockIdx.x;
  #pragma unroll
  for (int k = 0; k < 10; k++) {
    const KJob job = J.j[k];
    const int nb = (job.n4 + 255) >> 8;
    if (bi >= job.blk0 && bi < job.blk0 + nb) {
      const int i = (bi - job.blk0) * 256 + threadIdx.x;
      if (i < job.n4) {
        ushort4 o = {0, 0, 0, 0};
        bool valid = true;
        if (job.xp) valid = ((i * 4) >> 11) < (kDtRank + 2 * kDS);
        if (valid) {
          const float4 v = ((const float4*)job.s)[i];
          o.x = f2bf(v.x); o.y = f2bf(v.y); o.z = f2bf(v.z); o.w = f2bf(v.w);
        }
        ((ushort4*)job.d)[i] = o;
      }
      return;
    }
  }
}

// ---------------------------------------------------------------------------
// bf16 MFMA GEMM (2-phase): TILEN=128 (4 waves 2x2, 64x64/wave) or
// TILEN=64 (4 waves 4x1, 32x64/wave; for N=1024 GEMMs).
// ---------------------------------------------------------------------------
template <int TILEN, int ACT, bool BIAS, bool ACC, bool OUTBF, bool REV,
          bool AMAP, bool CMAP>
__global__ __launch_bounds__(256) void gemm_mfma(
    const u16* __restrict__ A, int lda,
    const u16* __restrict__ W, int ldw,
    void* __restrict__ Cp, int ldc, int K,
    const float* __restrict__ bias, int seg_len, int row_off) {
  constexpr int MI = (TILEN == 128) ? 4 : 2;     // M-frags per wave
  constexpr int WSTR = TILEN / 32;               // W staging strips
  __shared__ __align__(16) u16 As[128][64];
  __shared__ __align__(16) u16 Ws[TILEN][64];
  const int tid  = threadIdx.x;
  const int bm   = blockIdx.x * 128;
  const int bn   = blockIdx.y * TILEN;
  const int lane = tid & 63;
  const int wv   = tid >> 6;
  const int wm   = (TILEN == 128) ? (wv >> 1) * 64 : wv * 32;
  const int wn   = (TILEN == 128) ? (wv & 1) * 64 : 0;
  const int l15  = lane & 15;
  const int quad = lane >> 4;
  const int srow = lane >> 3;
  const int swz  = ((lane & 7) ^ srow) * 8;
  const int jx   = (l15 & 7) * 16;

  int ab = 0, all0 = bm;
  if (AMAP || CMAP) {
    ab = bm / seg_len;
    all0 = bm - ab * seg_len;
  }

  int arowv[4];
  #pragma unroll
  for (int it = 0; it < 4; it++) {
    const int rl = it * 32 + wv * 8 + srow;
    if (AMAP) {
      arowv[it] = REV ? (ab * kL + kL - 1 - row_off - all0 - rl)
                      : (ab * kL + row_off + all0 + rl);
    } else {
      arowv[it] = bm + rl;
    }
  }

  f32x4 acc[MI][4];
  #pragma unroll
  for (int i = 0; i < MI; i++)
    #pragma unroll
    for (int j = 0; j < 4; j++) acc[i][j] = (f32x4){0.f, 0.f, 0.f, 0.f};

  for (int k0 = 0; k0 < K; k0 += 64) {
    #pragma unroll
    for (int it = 0; it < 4; it++) {
      const int rl = it * 32 + wv * 8 + srow;
      async16(A + (size_t)arowv[it] * lda + k0 + swz, &As[it * 32 + wv * 8][0]);
    }
    #pragma unroll
    for (int it = 0; it < WSTR; it++) {
      const int rl = it * 32 + wv * 8 + srow;
      async16(W + (size_t)(bn + rl) * ldw + k0 + swz, &Ws[it * 32 + wv * 8][0]);
    }
    __syncthreads();
    #pragma unroll
    for (int ks = 0; ks < 64; ks += 32) {
      const int cb = ((ks >> 3) + quad) * 16;
      bf16x8 af[MI], wf[4];
      #pragma unroll
      for (int i = 0; i < MI; i++)
        af[i] = *(const bf16x8*)((const char*)&As[wm + i * 16 + l15][0] +
                                 (cb ^ jx));
      #pragma unroll
      for (int j = 0; j < 4; j++)
        wf[j] = *(const bf16x8*)((const char*)&Ws[wn + j * 16 + l15][0] +
                                 (cb ^ jx));
      #pragma unroll
      for (int i = 0; i < MI; i++)
        #pragma unroll
        for (int j = 0; j < 4; j++)
          acc[i][j] = __builtin_amdgcn_mfma_f32_16x16x32_bf16(
              af[i], wf[j], acc[i][j], 0, 0, 0);
    }
    __syncthreads();
  }

  #pragma unroll
  for (int i = 0; i < MI; i++) {
    #pragma unroll
    for (int j = 0; j < 4; j++) {
      const int col = bn + wn + j * 16 + l15;
      #pragma unroll
      for (int r = 0; r < 4; r++) {
        const int rl2 = wm + i * 16 + quad * 4 + r;
        const int crow = CMAP ? (ab * kL + row_off + all0 + rl2) : (bm + rl2);
        float v = acc[i][j][r];
        if (BIAS) v += bias[col];
        if (ACT == 1) v = softplusf(v);
        if (ACT == 2) v = geluf(v);
        if (OUTBF) {
          ((u16*)Cp)[(size_t)crow * ldc + col] = f2bf(v);
        } else {
          float* p = (float*)Cp + (size_t)crow * ldc + col;
          if (ACC) *p = *p + v; else *p = v;
        }
      }
    }
  }
}

// ---------------------------------------------------------------------------
// x_proj split-K: dblp[kq] = xs[bm:bm+128, kq*256:(kq+1)*256] @ W^T partial.
// Grid (Mseg/128, 8).  Same 2-phase body; f32 partial output.
// ---------------------------------------------------------------------------
__global__ __launch_bounds__(256) void xproj_k8_kernel(
    const u16* __restrict__ A, const u16* __restrict__ W,
    float* __restrict__ xpp, int Mrows) {
  __shared__ __align__(16) u16 As[128][64];
  __shared__ __align__(16) u16 Ws[128][64];
  const int tid  = threadIdx.x;
  const int bm   = blockIdx.x * 128;
  const int kq   = blockIdx.y;          // 0..7 K-chunk
  const int lane = tid & 63;
  const int wv   = tid >> 6;
  const int wm   = (wv >> 1) * 64;
  const int wn   = (wv & 1) * 64;
  const int l15  = lane & 15;
  const int quad = lane >> 4;
  const int srow = lane >> 3;
  const int swz  = ((lane & 7) ^ srow) * 8;
  const int jx   = (l15 & 7) * 16;

  f32x4 acc[4][4];
  #pragma unroll
  for (int i = 0; i < 4; i++)
    #pragma unroll
    for (int j = 0; j < 4; j++) acc[i][j] = (f32x4){0.f, 0.f, 0.f, 0.f};

  const int kbeg = kq * 256;
  for (int k0 = kbeg; k0 < kbeg + 256; k0 += 64) {
    #pragma unroll
    for (int it = 0; it < 4; it++) {
      const int rl = it * 32 + wv * 8 + srow;
      async16(A + (size_t)(bm + rl) * kDI + k0 + swz, &As[it * 32 + wv * 8][0]);
      async16(W + (size_t)rl * kDI + k0 + swz, &Ws[it * 32 + wv * 8][0]);
    }
    __syncthreads();
    #pragma unroll
    for (int ks = 0; ks < 64; ks += 32) {
      const int cb = ((ks >> 3) + quad) * 16;
      bf16x8 af[4], wf[4];
      #pragma unroll
      for (int i = 0; i < 4; i++)
        af[i] = *(const bf16x8*)((const char*)&As[wm + i * 16 + l15][0] +
                                 (cb ^ jx));
      #pragma unroll
      for (int j = 0; j < 4; j++)
        wf[j] = *(const bf16x8*)((const char*)&Ws[wn + j * 16 + l15][0] +
                                 (cb ^ jx));
      #pragma unroll
      for (int i = 0; i < 4; i++)
        #pragma unroll
        for (int j = 0; j < 4; j++)
          acc[i][j] = __builtin_amdgcn_mfma_f32_16x16x32_bf16(
              af[i], wf[j], acc[i][j], 0, 0, 0);
    }
    __syncthreads();
  }

  float* outp = xpp + (size_t)kq * Mrows * kNPad;
  #pragma unroll
  for (int i = 0; i < 4; i++) {
    #pragma unroll
    for (int j = 0; j < 4; j++) {
      const int col = wn + j * 16 + l15;
      #pragma unroll
      for (int r = 0; r < 4; r++) {
        const int row = bm + wm + i * 16 + quad * 4 + r;
        outp[(size_t)row * kNPad + col] = acc[i][j][r];
      }
    }
  }
}

// reduce 8 f32 partials -> bf16 dbl
__global__ __launch_bounds__(256) void xproj_reduce_kernel(
    const float* __restrict__ xpp, u16* __restrict__ dbl, int n) {
  const int i = blockIdx.x * 256 + threadIdx.x;
  float s = 0.f;
  #pragma unroll
  for (int k = 0; k < 8; k++) s += xpp[(size_t)k * n + i];
  dbl[i] = f2bf(s);
}

// ---------------------------------------------------------------------------
// Dedicated dt_proj kernel: dtb = softplus(dbl[:, :64] @ dt_w^T + dt_b).
// ---------------------------------------------------------------------------
__global__ __launch_bounds__(256) void dt_kernel(
    const u16* __restrict__ dbl, const u16* __restrict__ wdt,
    const float* __restrict__ bias, u16* __restrict__ dtb) {
  __shared__ __align__(16) u16 sh[2][128][64];   // stage A/W; then C[128][128]
  const int tid  = threadIdx.x;
  const int bm   = blockIdx.x * 128;
  const int bn   = blockIdx.y * 128;
  const int lane = tid & 63;
  const int wv   = tid >> 6;
  const int wm   = (wv >> 1) * 64;
  const int wn   = (wv & 1) * 64;
  const int l15  = lane & 15;
  const int quad = lane >> 4;
  const int srow = lane >> 3;
  const int swz  = ((lane & 7) ^ srow) * 8;
  const int jx   = (l15 & 7) * 16;

  #pragma unroll
  for (int it = 0; it < 4; it++) {
    const int rl = it * 32 + wv * 8 + srow;
    async16(dbl + (size_t)(bm + rl) * kNPad + swz, &sh[0][it * 32 + wv * 8][0]);
    async16(wdt + (size_t)(bn + rl) * kDtRank + swz,
            &sh[1][it * 32 + wv * 8][0]);
  }
  __syncthreads();

  f32x4 acc[4][4];
  #pragma unroll
  for (int i = 0; i < 4; i++)
    #pragma unroll
    for (int j = 0; j < 4; j++) acc[i][j] = (f32x4){0.f, 0.f, 0.f, 0.f};

  #pragma unroll
  for (int ks = 0; ks < 2; ks++) {
    const int cb = (ks * 4 + quad) * 16;
    bf16x8 af[4], wf[4];
    #pragma unroll
    for (int i = 0; i < 4; i++)
      af[i] = *(const bf16x8*)((const char*)&sh[0][wm + i * 16 + l15][0] +
                               (cb ^ jx));
    #pragma unroll
    for (int j = 0; j < 4; j++)
      wf[j] = *(const bf16x8*)((const char*)&sh[1][wn + j * 16 + l15][0] +
                               (cb ^ jx));
    #pragma unroll
    for (int i = 0; i < 4; i++)
      #pragma unroll
      for (int j = 0; j < 4; j++)
        acc[i][j] = __builtin_amdgcn_mfma_f32_16x16x32_bf16(
            af[i], wf[j], acc[i][j], 0, 0, 0);
  }
  __syncthreads();   // all waves done reading staging LDS

  u16* C = &sh[0][0][0];   // alias as [128][128] u16 tile (exactly 32KB)
  #pragma unroll
  for (int i = 0; i < 4; i++) {
    #pragma unroll
    for (int j = 0; j < 4; j++) {
      const int colL = wn + j * 16 + l15;
      const float bv = bias[bn + colL];
      #pragma unroll
      for (int r = 0; r < 4; r++) {
        const int rl2 = wm + i * 16 + quad * 4 + r;
        C[rl2 * 128 + colL] = f2bf(softplus_fast(acc[i][j][r] + bv));
      }
    }
  }
  __syncthreads();

  #pragma unroll
  for (int i = 0; i < 8; i++) {
    const int cidx = i * 256 + tid;        // ushort8 chunk id, 2048 total
    const int row  = cidx >> 4;
    const int cin  = (cidx & 15) * 8;
    const ushort8 val = *(const ushort8*)&C[row * 128 + cin];
    *(ushort8*)&dtb[(size_t)(bm + row) * kDI + bn + cin] = val;
  }
}

// ---------------------------------------------------------------------------
// Causal depthwise conv (k=4) + bias + silu on one segment (compact rows).
// ---------------------------------------------------------------------------
__global__ __launch_bounds__(256) void conv_silu_kernel(
    const u16* __restrict__ xz, const float* __restrict__ w,
    const float* __restrict__ cb, u16* __restrict__ xs,
    const u16* __restrict__ tail_in, u16* __restrict__ tail_out,
    int seg_len, int row_off) {
  const int t = blockIdx.x * 256 + threadIdx.x;  // Mseg*kDI threads
  const int c = t & (kDI - 1);
  const int r = t >> 11;              // compact row
  const int b = r / seg_len;
  const int ll = r - b * seg_len;
  const int tpos = row_off + ll;      // processing-order position in [0,L)

  const float xv0 = bf2f(xz[(size_t)r * (2 * kDI) + c]);
  float acc = cb[c] + w[c * 4 + 3] * xv0;
  #pragma unroll
  for (int j = 1; j <= 3; j++) {
    if (tpos - j >= 0) {
      float xp;
      if (ll - j >= 0) {
        xp = bf2f(xz[(size_t)(r - j) * (2 * kDI) + c]);
      } else {
        xp = bf2f(tail_in[(b * 3 + (3 + ll - j)) * kDI + c]);
      }
      acc += w[c * 4 + 3 - j] * xp;
    }
  }
  xs[(size_t)r * kDI + c] = f2bf(siluf(acc));
  if (ll >= seg_len - 3) {
    tail_out[(b * 3 + (ll - (seg_len - 3))) * kDI + c] = f2bf(xv0);
  }
}

// ---------------------------------------------------------------------------
// Scan phase A: per (b, c, chunk), 16 states in registers, no cross-lane.
// ---------------------------------------------------------------------------
__global__ __launch_bounds__(256, 8) void scan_phaseA(
    const u16* __restrict__ dt, const u16* __restrict__ xs,
    const u16* __restrict__ dbl, const float* __restrict__ Alog,
    float* __restrict__ Pbuf, float* __restrict__ Hbuf,
    int Lseg, int Lc) {
  __shared__ float Bls[32][16];
  const int tid = threadIdx.x;
  const int c = blockIdx.x * 256 + tid;
  const int k = blockIdx.y;
  const int b = blockIdx.z;
  const int base = b * Lseg + k * Lc;
  for (int idx = tid; idx < Lc * 16; idx += 256) {
    const int r = idx >> 4, j = idx & 15;
    Bls[r][j] = bf2f(dbl[(size_t)(base + r) * kNPad + kDtRank + j]);
  }
  __syncthreads();
  float Ac[16], h[16];
  float dtsum = 0.f;
  #pragma unroll
  for (int s = 0; s < 16; s++) {
    Ac[s] = -__expf(Alog[c * kDS + s]) * 1.44269504088896f;  // *log2(e)
    h[s] = 0.f;
  }
  for (int r = 0; r < Lc; r++) {
    const size_t row = (size_t)(base + r);
    const float dtv = bf2f(dt[row * kDI + c]);
    const float dtx = dtv * bf2f(xs[row * kDI + c]);
    dtsum += dtv;
    const float4* Brow = (const float4*)Bls[r];
    #pragma unroll
    for (int s4 = 0; s4 < 4; s4++) {
      const float4 Bv = Brow[s4];
      const float bb[4] = {Bv.x, Bv.y, Bv.z, Bv.w};
      #pragma unroll
      for (int q = 0; q < 4; q++) {
        const int s = s4 * 4 + q;
        const float dA = exp2_fast(dtv * Ac[s]);
        h[s] = dA * h[s] + dtx * bb[q];
      }
    }
  }
  const size_t o = (((size_t)b * kNCH + k) * kDI + c) * 16;
  #pragma unroll
  for (int s4 = 0; s4 < 4; s4++) {
    *(float4*)&Pbuf[o + s4 * 4] =
        make_float4(exp2_fast(Ac[s4 * 4 + 0] * dtsum),
                    exp2_fast(Ac[s4 * 4 + 1] * dtsum),
                    exp2_fast(Ac[s4 * 4 + 2] * dtsum),
                    exp2_fast(Ac[s4 * 4 + 3] * dtsum));
    *(float4*)&Hbuf[o + s4 * 4] =
        make_float4(h[s4 * 4], h[s4 * 4 + 1], h[s4 * 4 + 2], h[s4 * 4 + 3]);
  }
}

// ---------------------------------------------------------------------------
// Scan phase B: stitch chunks; h_in per chunk written over Pbuf.
// ---------------------------------------------------------------------------
__global__ __launch_bounds__(256) void scan_phaseB(
    float* __restrict__ Pbuf, const float* __restrict__ Hbuf,
    float* __restrict__ hstate, int first) {
  const int t = blockIdx.x * 256 + threadIdx.x;  // B*di*16
  const int s = t & 15;
  const int c = (t >> 4) & (kDI - 1);
  const int b = t >> 15;
  float cur = first ? 0.f : hstate[t];
  for (int k = 0; k < kNCH; k++) {
    const size_t idx = (((size_t)b * kNCH + k) * kDI + c) * 16 + s;
    const float p = Pbuf[idx];
    const float hl = Hbuf[idx];
    Pbuf[idx] = cur;
    cur = p * cur + hl;
  }
  hstate[t] = cur;
}

// ---------------------------------------------------------------------------
// Scan phase C: re-run chunk with true h_in, y = C.h + D*x, *silu(z) -> xs.
// ---------------------------------------------------------------------------
__global__ __launch_bounds__(256, 8) void scan_phaseC(
    const u16* __restrict__ dt, u16* __restrict__ xs,
    const u16* __restrict__ dbl, const u16* __restrict__ xz,
    const float* __restrict__ Alog, const float* __restrict__ Dp,
    const float* __restrict__ Pbuf, int Lseg, int Lc) {
  __shared__ float BC[32][32];  // [r][0:16]=B, [r][16:32]=C
  const int tid = threadIdx.x;
  const int c = blockIdx.x * 256 + tid;
  const int k = blockIdx.y;
  const int b = blockIdx.z;
  const int base = b * Lseg + k * Lc;
  for (int idx = tid; idx < Lc * 32; idx += 256) {
    const int r = idx >> 5, j = idx & 31;
    BC[r][j] = bf2f(dbl[(size_t)(base + r) * kNPad + kDtRank + j]);
  }
  __syncthreads();
  float Ac[16], h[16];
  const size_t o = (((size_t)b * kNCH + k) * kDI + c) * 16;
  #pragma unroll
  for (int s4 = 0; s4 < 4; s4++) {
    const float4 hv = *(const float4*)&Pbuf[o + s4 * 4];
    h[s4 * 4 + 0] = hv.x; h[s4 * 4 + 1] = hv.y;
    h[s4 * 4 + 2] = hv.z; h[s4 * 4 + 3] = hv.w;
  }
  #pragma unroll
  for (int s = 0; s < 16; s++)
    Ac[s] = -__expf(Alog[c * kDS + s]) * 1.44269504088896f;  // *log2(e)
  const float Dv = Dp[c];
  for (int r = 0; r < Lc; r++) {
    const size_t row = (size_t)(base + r);
    const float dtv = bf2f(dt[row * kDI + c]);
    const float xv = bf2f(xs[row * kDI + c]);
    const float dtx = dtv * xv;
    float y = 0.f;
    const float4* Brow = (const float4*)BC[r];
    const float4* Crow = (const float4*)&BC[r][16];
    #pragma unroll
    for (int s4 = 0; s4 < 4; s4++) {
      const float4 Bv = Brow[s4];
      const float4 Cv = Crow[s4];
      const float bb[4] = {Bv.x, Bv.y, Bv.z, Bv.w};
      const float cc[4] = {Cv.x, Cv.y, Cv.z, Cv.w};
      #pragma unroll
      for (int q = 0; q < 4; q++) {
        const int s = s4 * 4 + q;
        const float dA = exp2_fast(dtv * Ac[s]);
        h[s] = dA * h[s] + dtx * bb[q];
        y += h[s] * cc[q];
      }
    }
    const float z = bf2f(xz[row * (2 * kDI) + kDI + c]);
    xs[row * kDI + c] = f2bf((y + Dv * xv) * siluf(z));
  }
}

}  // namespace

extern "C" void kernel_launch(void* const* d_in, const int* in_sizes, int n_in,
                              void* d_out, int out_size, void* d_ws,
                              size_t ws_size, hipStream_t stream) {
  const float* x = (const float*)d_in[0];
  const float* in_w[2]    = {(const float*)d_in[1],  (const float*)d_in[10]};
  const float* conv_w[2]  = {(const float*)d_in[2],  (const float*)d_in[11]};
  const float* conv_b[2]  = {(const float*)d_in[3],  (const float*)d_in[12]};
  const float* xproj_w[2] = {(const float*)d_in[4],  (const float*)d_in[13]};
  const float* dt_w[2]    = {(const float*)d_in[5],  (const float*)d_in[14]};
  const float* dt_b[2]    = {(const float*)d_in[6],  (const float*)d_in[15]};
  const float* Alog[2]    = {(const float*)d_in[7],  (const float*)d_in[16]};
  const float* Dp[2]      = {(const float*)d_in[8],  (const float*)d_in[17]};
  const float* out_w[2]   = {(const float*)d_in[9],  (const float*)d_in[18]};
  const float* norm_g = (const float*)d_in[19];
  const float* norm_b = (const float*)d_in[20];
  const float* ffn_g  = (const float*)d_in[21];
  const float* ffn_b  = (const float*)d_in[22];
  const float* ff1_w  = (const float*)d_in[23];
  const float* ff1_b  = (const float*)d_in[24];
  const float* ff2_w  = (const float*)d_in[25];
  const float* ff2_b  = (const float*)d_in[26];
  float* out = (float*)d_out;

  // --- adaptive workspace layout ---------------------------------------
  constexpr size_t kWCache =
      2 * ((size_t)4096 * kD + (size_t)kD * kDI + (size_t)kNPad * kDI +
           (size_t)kDI * kDtRank) * 2 +
      ((size_t)kDFF * kD + (size_t)kD * kDFF) * 2;  // bf16 weights
  auto need = [](int nseg) -> size_t {
    const size_t mseg = (size_t)kM / nseg;
    size_t sz = kWCache + 4096;
    sz += (size_t)kM * kD * 2;            // h bf16
    sz += mseg * 4096 * 2;                // xz bf16 (aliases FFN hidden)
    sz += mseg * 2048 * 2;                // xs bf16
    sz += mseg * 128 * 2;                 // dbl bf16
    sz += mseg * 2048 * 2;                // dt bf16
    sz += 8 * mseg * 128 * 4;             // x_proj split-K partials (f32)
    sz += 2 * (size_t)kB * kNCH * kDI * kDS * 4;  // Pbuf + Hbuf
    sz += (size_t)kB * kDI * kDS * 4;     // hstate
    sz += 2 * (size_t)kB * 3 * kDI * 2;   // conv tails
    sz += 32 * 256;                       // alignment slack
    return sz;
  };
  int nseg = 1;
  while (nseg <= 16 && need(nseg) > ws_size) nseg *= 2;
  if (nseg > 16) return;  // clean fail
  const int Lseg = kL / nseg;
  const int Mseg = kM / nseg;
  const int Lc = Lseg / kNCH;

  char* base = (char*)d_ws;
  size_t off = 0;
  auto alloc = [&](size_t bytes) {
    char* p = base + off;
    off = (off + bytes + 255) & ~(size_t)255;
    return p;
  };
  // bf16 weight cache
  u16* w_in[2], *w_out[2], *w_xp[2], *w_dt[2];
  for (int m = 0; m < 2; m++) {
    w_in[m]  = (u16*)alloc((size_t)4096 * kD * 2);
    w_out[m] = (u16*)alloc((size_t)kD * kDI * 2);
    w_xp[m]  = (u16*)alloc((size_t)kNPad * kDI * 2);
    w_dt[m]  = (u16*)alloc((size_t)kDI * kDtRank * 2);
  }
  u16* w_f1 = (u16*)alloc((size_t)kDFF * kD * 2);
  u16* w_f2 = (u16*)alloc((size_t)kD * kDFF * 2);
  // activations
  u16*   h      = (u16*)alloc((size_t)kM * kD * 2);
  u16*   xz     = (u16*)alloc((size_t)Mseg * 4096 * 2);
  u16*   xs     = (u16*)alloc((size_t)Mseg * 2048 * 2);
  u16*   dbl    = (u16*)alloc((size_t)Mseg * 128 * 2);
  u16*   dtb    = (u16*)alloc((size_t)Mseg * 2048 * 2);
  float* xpp    = (float*)alloc((size_t)8 * Mseg * 128 * 4);
  float* Pbuf   = (float*)alloc((size_t)kB * kNCH * kDI * kDS * 4);
  float* Hbuf   = (float*)alloc((size_t)kB * kNCH * kDI * kDS * 4);
  float* hstate = (float*)alloc((size_t)kB * kDI * kDS * 4);
  u16*   tail0  = (u16*)alloc((size_t)kB * 3 * kDI * 2);
  u16*   tail1  = (u16*)alloc((size_t)kB * 3 * kDI * 2);

  // fused weight conversion (once per call)
  {
    KJobs J;
    int b = 0, ji = 0;
    auto addjob = [&](const float* s, u16* d, int n4, int xp) {
      J.j[ji].s = s; J.j[ji].d = d; J.j[ji].n4 = n4;
      J.j[ji].blk0 = b; J.j[ji].xp = xp;
      b += (n4 + 255) >> 8;
      ji++;
    };
    for (int m = 0; m < 2; m++) {
      addjob(in_w[m],  w_in[m],  (4096 * kD) / 4, 0);
      addjob(out_w[m], w_out[m], (kD * kDI) / 4, 0);
      addjob(xproj_w[m], w_xp[m], (kNPad * kDI) / 4, 1);
      addjob(dt_w[m],  w_dt[m],  (kDI * kDtRank) / 4, 0);
    }
    addjob(ff1_w, w_f1, (kDFF * kD) / 4, 0);
    addjob(ff2_w, w_f2, (kD * kDFF) / 4, 0);
    cvt_all_kernel<<<b, 256, 0, stream>>>(J);
  }

  // LN(x) -> h (bf16)
  ln_kernel<<<kM, 256, 0, stream>>>(x, norm_g, norm_b, h);

  for (int m = 0; m < 2; m++) {
    for (int s = 0; s < nseg; s++) {
      const int l0 = s * Lseg;
      u16* tin  = (s & 1) ? tail0 : tail1;
      u16* tout = (s & 1) ? tail1 : tail0;
      // in_proj: h rows (REV for m=1) x in_w[4096,1024]^T -> xz [Mseg,4096]
      if (m == 0)
        gemm_mfma<128, 0, false, false, true, false, true, false>
            <<<dim3(Mseg / 128, 4096 / 128), 256, 0, stream>>>(
                h, kD, w_in[m], kD, xz, 4096, kD, nullptr, Lseg, l0);
      else
        gemm_mfma<128, 0, false, false, true, true, true, false>
            <<<dim3(Mseg / 128, 4096 / 128), 256, 0, stream>>>(
                h, kD, w_in[m], kD, xz, 4096, kD, nullptr, Lseg, l0);
      // causal depthwise conv + silu -> xs
      conv_silu_kernel<<<(Mseg * kDI) / 256, 256, 0, stream>>>(
          xz, conv_w[m], conv_b[m], xs, tin, tout, Lseg, l0);
      // x_proj: split-K x8 -> f32 partials -> reduce to bf16 dbl
      xproj_k8_kernel<<<dim3(Mseg / 128, 8), 256, 0, stream>>>(
          xs, w_xp[m], xpp, Mseg);
      xproj_reduce_kernel<<<(Mseg * kNPad) / 256, 256, 0, stream>>>(
          xpp, dbl, Mseg * kNPad);
      // dt_proj + softplus: dedicated kernel
      dt_kernel<<<dim3(Mseg / 128, kDI / 128), 256, 0, stream>>>(
          dbl, w_dt[m], dt_b[m], dtb);
      // chunked scan: A (local), B (stitch), C (emit y into xs)
      scan_phaseA<<<dim3(kDI / 256, kNCH, kB), 256, 0, stream>>>(
          dtb, xs, dbl, Alog[m], Pbuf, Hbuf, Lseg, Lc);
      scan_phaseB<<<(kB * kDI * kDS) / 256, 256, 0, stream>>>(
          Pbuf, Hbuf, hstate, (s == 0) ? 1 : 0);
      scan_phaseC<<<dim3(kDI / 256, kNCH, kB), 256, 0, stream>>>(
          dtb, xs, dbl, xz, Alog[m], Dp[m], Pbuf, Lseg, Lc);
      // out_proj -> d_out rows (f32); m=1 accumulates (TILEN=64 2-phase)
      if (m == 0)
        gemm_mfma<64, 0, false, false, false, false, false, true>
            <<<dim3(Mseg / 128, kD / 64), 256, 0, stream>>>(
                xs, kDI, w_out[m], kDI, out, kD, kDI, nullptr, Lseg, l0);
      else
        gemm_mfma<64, 0, false, true, false, false, false, true>
            <<<dim3(Mseg / 128, kD / 64), 256, 0, stream>>>(
                xs, kDI, w_out[m], kDI, out, kD, kDI, nullptr, Lseg, l0);
    }
  }

  // x2 = x + gelu(fwd + bwd + x) in place on d_out; h = LN(x2) (fused)
  combine_ln_kernel<<<kM, 256, 0, stream>>>(x, out, ffn_g, ffn_b, h);

  // FFN: per M-segment: hidden = gelu(h@ff1^T+b1) (alias xz);
  // out += hidden@ff2^T + b2
  for (int s = 0; s < nseg; s++) {
    const int r0 = s * Mseg;
    gemm_mfma<128, 2, true, false, true, false, true, false>
        <<<dim3(Mseg / 128, kDFF / 128), 256, 0, stream>>>(
            h, kD, w_f1, kD, xz, kDFF, kD, ff1_b, Mseg, r0);
    gemm_mfma<64, 0, true, true, false, false, false, true>
        <<<dim3(Mseg / 128, kD / 64), 256, 0, stream>>>(
            xz, kDFF, w_f2, kDFF, out, kD, kDFF, ff2_b, Mseg, r0);
  }
}

// Round 10
// 1177.397 us; speedup vs baseline: 1.2979x; 1.2243x over previous
//
#include <hip/hip_runtime.h>
#include <cmath>

// ---------------------------------------------------------------------------
// BiDirectionalAddFFBlock: LN -> mamba(fwd)+mamba(rev) -> gelu residual ->
// LN -> FFN.  B=4, L=2048, D=1024, di=2048, ds=16, dt_rank=64, DFF=4096.
// Round 16: R15's 32MB xpp allocation pushed need(1) > ws_size -> silent
// nseg=2 (counters: out_proj WRITE=16384KB=4096x1024 f32, 512-block grids,
// MfmaUtil 15%).  Fix: xpp ALIASES Pbuf -- live ranges are disjoint
// (xpp: xproj_k8..xproj_reduce; Pbuf: scanA..scanC) and sizes are exactly
// equal (8*8192*128*4 == 4*64*2048*16*4 == 32MB).  need() back to the R12
// budget -> nseg=1.  Split-K x_proj kept at zero workspace cost.
// ---------------------------------------------------------------------------

namespace {

using u16 = unsigned short;
using uint = unsigned int;

constexpr int kB = 4;
constexpr int kL = 2048;
constexpr int kD = 1024;
constexpr int kDI = 2048;
constexpr int kDFF = 4096;
constexpr int kDS = 16;
constexpr int kDtRank = 64;
constexpr int kNPad = 128;       // x_proj N=96 padded to 128
constexpr int kM = kB * kL;      // 8192 rows
constexpr int kNCH = 64;         // scan chunks per segment

typedef short bf16x8 __attribute__((ext_vector_type(8)));
typedef float f32x4  __attribute__((ext_vector_type(4)));
typedef unsigned short ushort8 __attribute__((ext_vector_type(8)));

__device__ __forceinline__ float bf2f(u16 u) {
  union { unsigned int i; float f; } c; c.i = ((unsigned int)u) << 16; return c.f;
}
__device__ __forceinline__ u16 f2bf(float f) {  // round-to-nearest-even
  union { float f; unsigned int i; } c; c.f = f;
  return (u16)((c.i + 0x7FFFu + ((c.i >> 16) & 1u)) >> 16);
}
__device__ __forceinline__ float geluf(float v) {
  return 0.5f * v * (1.f + erff(v * 0.70710678118654752f));
}
__device__ __forceinline__ float softplusf(float v) {
  return (v > 0.f) ? (v + log1pf(__expf(-v))) : log1pf(__expf(v));
}
__device__ __forceinline__ float siluf(float v) {
  return v / (1.f + __expf(-v));
}
__device__ __forceinline__ float exp2_fast(float v) {
  return __builtin_amdgcn_exp2f(v);
}
// branch-free softplus: max(v,0) + ln(1 + e^{-|v|});  v_exp_f32 + v_log_f32.
__device__ __forceinline__ float softplus_fast(float v) {
  const float a = __builtin_fabsf(v);
  const float e = exp2_fast(-a * 1.44269504088896f);
  const float l = __log2f(1.f + e) * 0.69314718055995f;
  return fmaxf(v, 0.f) + l;
}

// async 16B global -> LDS (dest = wave-uniform lds base + lane*16)
__device__ __forceinline__ void async16(const u16* g, u16* l) {
  __builtin_amdgcn_global_load_lds(
      (const __attribute__((address_space(1))) uint*)g,
      (__attribute__((address_space(3))) uint*)l, 16, 0, 0);
}

// ---------------------------------------------------------------------------
// LayerNorm fp32 row (1024) -> bf16.  One block per row.
// ---------------------------------------------------------------------------
__global__ __launch_bounds__(256) void ln_kernel(
    const float* __restrict__ x, const float* __restrict__ g,
    const float* __restrict__ b, u16* __restrict__ out) {
  const int row = blockIdx.x;
  const int tid = threadIdx.x;
  const float4 v = ((const float4*)(x + (size_t)row * kD))[tid];
  float s  = v.x + v.y + v.z + v.w;
  float ss = v.x * v.x + v.y * v.y + v.z * v.z + v.w * v.w;
  #pragma unroll
  for (int off = 32; off; off >>= 1) {
    s  += __shfl_xor(s, off);
    ss += __shfl_xor(ss, off);
  }
  __shared__ float ls[4], lss[4];
  const int wid = tid >> 6;
  if ((tid & 63) == 0) { ls[wid] = s; lss[wid] = ss; }
  __syncthreads();
  s  = ls[0] + ls[1] + ls[2] + ls[3];
  ss = lss[0] + lss[1] + lss[2] + lss[3];
  const float mu  = s * (1.f / kD);
  const float inv = rsqrtf(ss * (1.f / kD) - mu * mu + 1e-5f);
  const float4 gg = ((const float4*)g)[tid];
  const float4 bb = ((const float4*)b)[tid];
  ushort4 o;
  o.x = f2bf((v.x - mu) * inv * gg.x + bb.x);
  o.y = f2bf((v.y - mu) * inv * gg.y + bb.y);
  o.z = f2bf((v.z - mu) * inv * gg.z + bb.z);
  o.w = f2bf((v.w - mu) * inv * gg.w + bb.w);
  ((ushort4*)(out + (size_t)row * kD))[tid] = o;
}

// combined: out = x + gelu(out + x); h = LN(out) bf16.  One block per row.
__global__ __launch_bounds__(256) void combine_ln_kernel(
    const float* __restrict__ x, float* __restrict__ out,
    const float* __restrict__ g, const float* __restrict__ b,
    u16* __restrict__ h) {
  const int row = blockIdx.x;
  const int tid = threadIdx.x;
  const float4 xv = ((const float4*)(x + (size_t)row * kD))[tid];
  const float4 bv = ((const float4*)(out + (size_t)row * kD))[tid];
  float4 o;
  o.x = xv.x + geluf(bv.x + xv.x);
  o.y = xv.y + geluf(bv.y + xv.y);
  o.z = xv.z + geluf(bv.z + xv.z);
  o.w = xv.w + geluf(bv.w + xv.w);
  ((float4*)(out + (size_t)row * kD))[tid] = o;
  float s  = o.x + o.y + o.z + o.w;
  float ss = o.x * o.x + o.y * o.y + o.z * o.z + o.w * o.w;
  #pragma unroll
  for (int off = 32; off; off >>= 1) {
    s  += __shfl_xor(s, off);
    ss += __shfl_xor(ss, off);
  }
  __shared__ float ls[4], lss[4];
  const int wid = tid >> 6;
  if ((tid & 63) == 0) { ls[wid] = s; lss[wid] = ss; }
  __syncthreads();
  s  = ls[0] + ls[1] + ls[2] + ls[3];
  ss = lss[0] + lss[1] + lss[2] + lss[3];
  const float mu  = s * (1.f / kD);
  const float inv = rsqrtf(ss * (1.f / kD) - mu * mu + 1e-5f);
  const float4 gg = ((const float4*)g)[tid];
  const float4 bb = ((const float4*)b)[tid];
  ushort4 ho;
  ho.x = f2bf((o.x - mu) * inv * gg.x + bb.x);
  ho.y = f2bf((o.y - mu) * inv * gg.y + bb.y);
  ho.z = f2bf((o.z - mu) * inv * gg.z + bb.z);
  ho.w = f2bf((o.w - mu) * inv * gg.w + bb.w);
  ((ushort4*)(h + (size_t)row * kD))[tid] = ho;
}

// ---------------------------------------------------------------------------
// Fused weight conversion: all fp32->bf16 weight jobs in one launch.
// ---------------------------------------------------------------------------
struct KJob { const float* s; u16* d; int n4; int blk0; int xp; };
struct KJobs { KJob j[10]; };

__global__ __launch_bounds__(256) void cvt_all_kernel(KJobs J) {
  const int bi = blockIdx.x;
  #pragma unroll
  for (int k = 0; k < 10; k++) {
    const KJob job = J.j[k];
    const int nb = (job.n4 + 255) >> 8;
    if (bi >= job.blk0 && bi < job.blk0 + nb) {
      const int i = (bi - job.blk0) * 256 + threadIdx.x;
      if (i < job.n4) {
        ushort4 o = {0, 0, 0, 0};
        bool valid = true;
        if (job.xp) valid = ((i * 4) >> 11) < (kDtRank + 2 * kDS);
        if (valid) {
          const float4 v = ((const float4*)job.s)[i];
          o.x = f2bf(v.x); o.y = f2bf(v.y); o.z = f2bf(v.z); o.w = f2bf(v.w);
        }
        ((ushort4*)job.d)[i] = o;
      }
      return;
    }
  }
}

// ---------------------------------------------------------------------------
// bf16 MFMA GEMM (2-phase): TILEN=128 (4 waves 2x2, 64x64/wave) or
// TILEN=64 (4 waves 4x1, 32x64/wave; for N=1024 GEMMs).
// ---------------------------------------------------------------------------
template <int TILEN, int ACT, bool BIAS, bool ACC, bool OUTBF, bool REV,
          bool AMAP, bool CMAP>
__global__ __launch_bounds__(256) void gemm_mfma(
    const u16* __restrict__ A, int lda,
    const u16* __restrict__ W, int ldw,
    void* __restrict__ Cp, int ldc, int K,
    const float* __restrict__ bias, int seg_len, int row_off) {
  constexpr int MI = (TILEN == 128) ? 4 : 2;     // M-frags per wave
  constexpr int WSTR = TILEN / 32;               // W staging strips
  __shared__ __align__(16) u16 As[128][64];
  __shared__ __align__(16) u16 Ws[TILEN][64];
  const int tid  = threadIdx.x;
  const int bm   = blockIdx.x * 128;
  const int bn   = blockIdx.y * TILEN;
  const int lane = tid & 63;
  const int wv   = tid >> 6;
  const int wm   = (TILEN == 128) ? (wv >> 1) * 64 : wv * 32;
  const int wn   = (TILEN == 128) ? (wv & 1) * 64 : 0;
  const int l15  = lane & 15;
  const int quad = lane >> 4;
  const int srow = lane >> 3;
  const int swz  = ((lane & 7) ^ srow) * 8;
  const int jx   = (l15 & 7) * 16;

  int ab = 0, all0 = bm;
  if (AMAP || CMAP) {
    ab = bm / seg_len;
    all0 = bm - ab * seg_len;
  }

  int arowv[4];
  #pragma unroll
  for (int it = 0; it < 4; it++) {
    const int rl = it * 32 + wv * 8 + srow;
    if (AMAP) {
      arowv[it] = REV ? (ab * kL + kL - 1 - row_off - all0 - rl)
                      : (ab * kL + row_off + all0 + rl);
    } else {
      arowv[it] = bm + rl;
    }
  }

  f32x4 acc[MI][4];
  #pragma unroll
  for (int i = 0; i < MI; i++)
    #pragma unroll
    for (int j = 0; j < 4; j++) acc[i][j] = (f32x4){0.f, 0.f, 0.f, 0.f};

  for (int k0 = 0; k0 < K; k0 += 64) {
    #pragma unroll
    for (int it = 0; it < 4; it++) {
      const int rl = it * 32 + wv * 8 + srow;
      async16(A + (size_t)arowv[it] * lda + k0 + swz, &As[it * 32 + wv * 8][0]);
    }
    #pragma unroll
    for (int it = 0; it < WSTR; it++) {
      const int rl = it * 32 + wv * 8 + srow;
      async16(W + (size_t)(bn + rl) * ldw + k0 + swz, &Ws[it * 32 + wv * 8][0]);
    }
    __syncthreads();
    #pragma unroll
    for (int ks = 0; ks < 64; ks += 32) {
      const int cb = ((ks >> 3) + quad) * 16;
      bf16x8 af[MI], wf[4];
      #pragma unroll
      for (int i = 0; i < MI; i++)
        af[i] = *(const bf16x8*)((const char*)&As[wm + i * 16 + l15][0] +
                                 (cb ^ jx));
      #pragma unroll
      for (int j = 0; j < 4; j++)
        wf[j] = *(const bf16x8*)((const char*)&Ws[wn + j * 16 + l15][0] +
                                 (cb ^ jx));
      #pragma unroll
      for (int i = 0; i < MI; i++)
        #pragma unroll
        for (int j = 0; j < 4; j++)
          acc[i][j] = __builtin_amdgcn_mfma_f32_16x16x32_bf16(
              af[i], wf[j], acc[i][j], 0, 0, 0);
    }
    __syncthreads();
  }

  #pragma unroll
  for (int i = 0; i < MI; i++) {
    #pragma unroll
    for (int j = 0; j < 4; j++) {
      const int col = bn + wn + j * 16 + l15;
      #pragma unroll
      for (int r = 0; r < 4; r++) {
        const int rl2 = wm + i * 16 + quad * 4 + r;
        const int crow = CMAP ? (ab * kL + row_off + all0 + rl2) : (bm + rl2);
        float v = acc[i][j][r];
        if (BIAS) v += bias[col];
        if (ACT == 1) v = softplusf(v);
        if (ACT == 2) v = geluf(v);
        if (OUTBF) {
          ((u16*)Cp)[(size_t)crow * ldc + col] = f2bf(v);
        } else {
          float* p = (float*)Cp + (size_t)crow * ldc + col;
          if (ACC) *p = *p + v; else *p = v;
        }
      }
    }
  }
}

// ---------------------------------------------------------------------------
// x_proj split-K: dblp[kq] = xs[bm:bm+128, kq*256:(kq+1)*256] @ W^T partial.
// Grid (Mseg/128, 8).  Same 2-phase body; f32 partial output.
// ---------------------------------------------------------------------------
__global__ __launch_bounds__(256) void xproj_k8_kernel(
    const u16* __restrict__ A, const u16* __restrict__ W,
    float* __restrict__ xpp, int Mrows) {
  __shared__ __align__(16) u16 As[128][64];
  __shared__ __align__(16) u16 Ws[128][64];
  const int tid  = threadIdx.x;
  const int bm   = blockIdx.x * 128;
  const int kq   = blockIdx.y;          // 0..7 K-chunk
  const int lane = tid & 63;
  const int wv   = tid >> 6;
  const int wm   = (wv >> 1) * 64;
  const int wn   = (wv & 1) * 64;
  const int l15  = lane & 15;
  const int quad = lane >> 4;
  const int srow = lane >> 3;
  const int swz  = ((lane & 7) ^ srow) * 8;
  const int jx   = (l15 & 7) * 16;

  f32x4 acc[4][4];
  #pragma unroll
  for (int i = 0; i < 4; i++)
    #pragma unroll
    for (int j = 0; j < 4; j++) acc[i][j] = (f32x4){0.f, 0.f, 0.f, 0.f};

  const int kbeg = kq * 256;
  for (int k0 = kbeg; k0 < kbeg + 256; k0 += 64) {
    #pragma unroll
    for (int it = 0; it < 4; it++) {
      const int rl = it * 32 + wv * 8 + srow;
      async16(A + (size_t)(bm + rl) * kDI + k0 + swz, &As[it * 32 + wv * 8][0]);
      async16(W + (size_t)rl * kDI + k0 + swz, &Ws[it * 32 + wv * 8][0]);
    }
    __syncthreads();
    #pragma unroll
    for (int ks = 0; ks < 64; ks += 32) {
      const int cb = ((ks >> 3) + quad) * 16;
      bf16x8 af[4], wf[4];
      #pragma unroll
      for (int i = 0; i < 4; i++)
        af[i] = *(const bf16x8*)((const char*)&As[wm + i * 16 + l15][0] +
                                 (cb ^ jx));
      #pragma unroll
      for (int j = 0; j < 4; j++)
        wf[j] = *(const bf16x8*)((const char*)&Ws[wn + j * 16 + l15][0] +
                                 (cb ^ jx));
      #pragma unroll
      for (int i = 0; i < 4; i++)
        #pragma unroll
        for (int j = 0; j < 4; j++)
          acc[i][j] = __builtin_amdgcn_mfma_f32_16x16x32_bf16(
              af[i], wf[j], acc[i][j], 0, 0, 0);
    }
    __syncthreads();
  }

  float* outp = xpp + (size_t)kq * Mrows * kNPad;
  #pragma unroll
  for (int i = 0; i < 4; i++) {
    #pragma unroll
    for (int j = 0; j < 4; j++) {
      const int col = wn + j * 16 + l15;
      #pragma unroll
      for (int r = 0; r < 4; r++) {
        const int row = bm + wm + i * 16 + quad * 4 + r;
        outp[(size_t)row * kNPad + col] = acc[i][j][r];
      }
    }
  }
}

// reduce 8 f32 partials -> bf16 dbl
__global__ __launch_bounds__(256) void xproj_reduce_kernel(
    const float* __restrict__ xpp, u16* __restrict__ dbl, int n) {
  const int i = blockIdx.x * 256 + threadIdx.x;
  float s = 0.f;
  #pragma unroll
  for (int k = 0; k < 8; k++) s += xpp[(size_t)k * n + i];
  dbl[i] = f2bf(s);
}

// ---------------------------------------------------------------------------
// Dedicated dt_proj kernel: dtb = softplus(dbl[:, :64] @ dt_w^T + dt_b).
// ---------------------------------------------------------------------------
__global__ __launch_bounds__(256) void dt_kernel(
    const u16* __restrict__ dbl, const u16* __restrict__ wdt,
    const float* __restrict__ bias, u16* __restrict__ dtb) {
  __shared__ __align__(16) u16 sh[2][128][64];   // stage A/W; then C[128][128]
  const int tid  = threadIdx.x;
  const int bm   = blockIdx.x * 128;
  const int bn   = blockIdx.y * 128;
  const int lane = tid & 63;
  const int wv   = tid >> 6;
  const int wm   = (wv >> 1) * 64;
  const int wn   = (wv & 1) * 64;
  const int l15  = lane & 15;
  const int quad = lane >> 4;
  const int srow = lane >> 3;
  const int swz  = ((lane & 7) ^ srow) * 8;
  const int jx   = (l15 & 7) * 16;

  #pragma unroll
  for (int it = 0; it < 4; it++) {
    const int rl = it * 32 + wv * 8 + srow;
    async16(dbl + (size_t)(bm + rl) * kNPad + swz, &sh[0][it * 32 + wv * 8][0]);
    async16(wdt + (size_t)(bn + rl) * kDtRank + swz,
            &sh[1][it * 32 + wv * 8][0]);
  }
  __syncthreads();

  f32x4 acc[4][4];
  #pragma unroll
  for (int i = 0; i < 4; i++)
    #pragma unroll
    for (int j = 0; j < 4; j++) acc[i][j] = (f32x4){0.f, 0.f, 0.f, 0.f};

  #pragma unroll
  for (int ks = 0; ks < 2; ks++) {
    const int cb = (ks * 4 + quad) * 16;
    bf16x8 af[4], wf[4];
    #pragma unroll
    for (int i = 0; i < 4; i++)
      af[i] = *(const bf16x8*)((const char*)&sh[0][wm + i * 16 + l15][0] +
                               (cb ^ jx));
    #pragma unroll
    for (int j = 0; j < 4; j++)
      wf[j] = *(const bf16x8*)((const char*)&sh[1][wn + j * 16 + l15][0] +
                               (cb ^ jx));
    #pragma unroll
    for (int i = 0; i < 4; i++)
      #pragma unroll
      for (int j = 0; j < 4; j++)
        acc[i][j] = __builtin_amdgcn_mfma_f32_16x16x32_bf16(
            af[i], wf[j], acc[i][j], 0, 0, 0);
  }
  __syncthreads();   // all waves done reading staging LDS

  u16* C = &sh[0][0][0];   // alias as [128][128] u16 tile (exactly 32KB)
  #pragma unroll
  for (int i = 0; i < 4; i++) {
    #pragma unroll
    for (int j = 0; j < 4; j++) {
      const int colL = wn + j * 16 + l15;
      const float bv = bias[bn + colL];
      #pragma unroll
      for (int r = 0; r < 4; r++) {
        const int rl2 = wm + i * 16 + quad * 4 + r;
        C[rl2 * 128 + colL] = f2bf(softplus_fast(acc[i][j][r] + bv));
      }
    }
  }
  __syncthreads();

  #pragma unroll
  for (int i = 0; i < 8; i++) {
    const int cidx = i * 256 + tid;        // ushort8 chunk id, 2048 total
    const int row  = cidx >> 4;
    const int cin  = (cidx & 15) * 8;
    const ushort8 val = *(const ushort8*)&C[row * 128 + cin];
    *(ushort8*)&dtb[(size_t)(bm + row) * kDI + bn + cin] = val;
  }
}

// ---------------------------------------------------------------------------
// Causal depthwise conv (k=4) + bias + silu on one segment (compact rows).
// ---------------------------------------------------------------------------
__global__ __launch_bounds__(256) void conv_silu_kernel(
    const u16* __restrict__ xz, const float* __restrict__ w,
    const float* __restrict__ cb, u16* __restrict__ xs,
    const u16* __restrict__ tail_in, u16* __restrict__ tail_out,
    int seg_len, int row_off) {
  const int t = blockIdx.x * 256 + threadIdx.x;  // Mseg*kDI threads
  const int c = t & (kDI - 1);
  const int r = t >> 11;              // compact row
  const int b = r / seg_len;
  const int ll = r - b * seg_len;
  const int tpos = row_off + ll;      // processing-order position in [0,L)

  const float xv0 = bf2f(xz[(size_t)r * (2 * kDI) + c]);
  float acc = cb[c] + w[c * 4 + 3] * xv0;
  #pragma unroll
  for (int j = 1; j <= 3; j++) {
    if (tpos - j >= 0) {
      float xp;
      if (ll - j >= 0) {
        xp = bf2f(xz[(size_t)(r - j) * (2 * kDI) + c]);
      } else {
        xp = bf2f(tail_in[(b * 3 + (3 + ll - j)) * kDI + c]);
      }
      acc += w[c * 4 + 3 - j] * xp;
    }
  }
  xs[(size_t)r * kDI + c] = f2bf(siluf(acc));
  if (ll >= seg_len - 3) {
    tail_out[(b * 3 + (ll - (seg_len - 3))) * kDI + c] = f2bf(xv0);
  }
}

// ---------------------------------------------------------------------------
// Scan phase A: per (b, c, chunk), 16 states in registers, no cross-lane.
// ---------------------------------------------------------------------------
__global__ __launch_bounds__(256, 8) void scan_phaseA(
    const u16* __restrict__ dt, const u16* __restrict__ xs,
    const u16* __restrict__ dbl, const float* __restrict__ Alog,
    float* __restrict__ Pbuf, float* __restrict__ Hbuf,
    int Lseg, int Lc) {
  __shared__ float Bls[32][16];
  const int tid = threadIdx.x;
  const int c = blockIdx.x * 256 + tid;
  const int k = blockIdx.y;
  const int b = blockIdx.z;
  const int base = b * Lseg + k * Lc;
  for (int idx = tid; idx < Lc * 16; idx += 256) {
    const int r = idx >> 4, j = idx & 15;
    Bls[r][j] = bf2f(dbl[(size_t)(base + r) * kNPad + kDtRank + j]);
  }
  __syncthreads();
  float Ac[16], h[16];
  float dtsum = 0.f;
  #pragma unroll
  for (int s = 0; s < 16; s++) {
    Ac[s] = -__expf(Alog[c * kDS + s]) * 1.44269504088896f;  // *log2(e)
    h[s] = 0.f;
  }
  for (int r = 0; r < Lc; r++) {
    const size_t row = (size_t)(base + r);
    const float dtv = bf2f(dt[row * kDI + c]);
    const float dtx = dtv * bf2f(xs[row * kDI + c]);
    dtsum += dtv;
    const float4* Brow = (const float4*)Bls[r];
    #pragma unroll
    for (int s4 = 0; s4 < 4; s4++) {
      const float4 Bv = Brow[s4];
      const float bb[4] = {Bv.x, Bv.y, Bv.z, Bv.w};
      #pragma unroll
      for (int q = 0; q < 4; q++) {
        const int s = s4 * 4 + q;
        const float dA = exp2_fast(dtv * Ac[s]);
        h[s] = dA * h[s] + dtx * bb[q];
      }
    }
  }
  const size_t o = (((size_t)b * kNCH + k) * kDI + c) * 16;
  #pragma unroll
  for (int s4 = 0; s4 < 4; s4++) {
    *(float4*)&Pbuf[o + s4 * 4] =
        make_float4(exp2_fast(Ac[s4 * 4 + 0] * dtsum),
                    exp2_fast(Ac[s4 * 4 + 1] * dtsum),
                    exp2_fast(Ac[s4 * 4 + 2] * dtsum),
                    exp2_fast(Ac[s4 * 4 + 3] * dtsum));
    *(float4*)&Hbuf[o + s4 * 4] =
        make_float4(h[s4 * 4], h[s4 * 4 + 1], h[s4 * 4 + 2], h[s4 * 4 + 3]);
  }
}

// ---------------------------------------------------------------------------
// Scan phase B: stitch chunks; h_in per chunk written over Pbuf.
// ---------------------------------------------------------------------------
__global__ __launch_bounds__(256) void scan_phaseB(
    float* __restrict__ Pbuf, const float* __restrict__ Hbuf,
    float* __restrict__ hstate, int first) {
  const int t = blockIdx.x * 256 + threadIdx.x;  // B*di*16
  const int s = t & 15;
  const int c = (t >> 4) & (kDI - 1);
  const int b = t >> 15;
  float cur = first ? 0.f : hstate[t];
  for (int k = 0; k < kNCH; k++) {
    const size_t idx = (((size_t)b * kNCH + k) * kDI + c) * 16 + s;
    const float p = Pbuf[idx];
    const float hl = Hbuf[idx];
    Pbuf[idx] = cur;
    cur = p * cur + hl;
  }
  hstate[t] = cur;
}

// ---------------------------------------------------------------------------
// Scan phase C: re-run chunk with true h_in, y = C.h + D*x, *silu(z) -> xs.
// ---------------------------------------------------------------------------
__global__ __launch_bounds__(256, 8) void scan_phaseC(
    const u16* __restrict__ dt, u16* __restrict__ xs,
    const u16* __restrict__ dbl, const u16* __restrict__ xz,
    const float* __restrict__ Alog, const float* __restrict__ Dp,
    const float* __restrict__ Pbuf, int Lseg, int Lc) {
  __shared__ float BC[32][32];  // [r][0:16]=B, [r][16:32]=C
  const int tid = threadIdx.x;
  const int c = blockIdx.x * 256 + tid;
  const int k = blockIdx.y;
  const int b = blockIdx.z;
  const int base = b * Lseg + k * Lc;
  for (int idx = tid; idx < Lc * 32; idx += 256) {
    const int r = idx >> 5, j = idx & 31;
    BC[r][j] = bf2f(dbl[(size_t)(base + r) * kNPad + kDtRank + j]);
  }
  __syncthreads();
  float Ac[16], h[16];
  const size_t o = (((size_t)b * kNCH + k) * kDI + c) * 16;
  #pragma unroll
  for (int s4 = 0; s4 < 4; s4++) {
    const float4 hv = *(const float4*)&Pbuf[o + s4 * 4];
    h[s4 * 4 + 0] = hv.x; h[s4 * 4 + 1] = hv.y;
    h[s4 * 4 + 2] = hv.z; h[s4 * 4 + 3] = hv.w;
  }
  #pragma unroll
  for (int s = 0; s < 16; s++)
    Ac[s] = -__expf(Alog[c * kDS + s]) * 1.44269504088896f;  // *log2(e)
  const float Dv = Dp[c];
  for (int r = 0; r < Lc; r++) {
    const size_t row = (size_t)(base + r);
    const float dtv = bf2f(dt[row * kDI + c]);
    const float xv = bf2f(xs[row * kDI + c]);
    const float dtx = dtv * xv;
    float y = 0.f;
    const float4* Brow = (const float4*)BC[r];
    const float4* Crow = (const float4*)&BC[r][16];
    #pragma unroll
    for (int s4 = 0; s4 < 4; s4++) {
      const float4 Bv = Brow[s4];
      const float4 Cv = Crow[s4];
      const float bb[4] = {Bv.x, Bv.y, Bv.z, Bv.w};
      const float cc[4] = {Cv.x, Cv.y, Cv.z, Cv.w};
      #pragma unroll
      for (int q = 0; q < 4; q++) {
        const int s = s4 * 4 + q;
        const float dA = exp2_fast(dtv * Ac[s]);
        h[s] = dA * h[s] + dtx * bb[q];
        y += h[s] * cc[q];
      }
    }
    const float z = bf2f(xz[row * (2 * kDI) + kDI + c]);
    xs[row * kDI + c] = f2bf((y + Dv * xv) * siluf(z));
  }
}

}  // namespace

extern "C" void kernel_launch(void* const* d_in, const int* in_sizes, int n_in,
                              void* d_out, int out_size, void* d_ws,
                              size_t ws_size, hipStream_t stream) {
  const float* x = (const float*)d_in[0];
  const float* in_w[2]    = {(const float*)d_in[1],  (const float*)d_in[10]};
  const float* conv_w[2]  = {(const float*)d_in[2],  (const float*)d_in[11]};
  const float* conv_b[2]  = {(const float*)d_in[3],  (const float*)d_in[12]};
  const float* xproj_w[2] = {(const float*)d_in[4],  (const float*)d_in[13]};
  const float* dt_w[2]    = {(const float*)d_in[5],  (const float*)d_in[14]};
  const float* dt_b[2]    = {(const float*)d_in[6],  (const float*)d_in[15]};
  const float* Alog[2]    = {(const float*)d_in[7],  (const float*)d_in[16]};
  const float* Dp[2]      = {(const float*)d_in[8],  (const float*)d_in[17]};
  const float* out_w[2]   = {(const float*)d_in[9],  (const float*)d_in[18]};
  const float* norm_g = (const float*)d_in[19];
  const float* norm_b = (const float*)d_in[20];
  const float* ffn_g  = (const float*)d_in[21];
  const float* ffn_b  = (const float*)d_in[22];
  const float* ff1_w  = (const float*)d_in[23];
  const float* ff1_b  = (const float*)d_in[24];
  const float* ff2_w  = (const float*)d_in[25];
  const float* ff2_b  = (const float*)d_in[26];
  float* out = (float*)d_out;

  // --- adaptive workspace layout ---------------------------------------
  // NOTE: x_proj split-K partials (xpp, 32MB at nseg=1) ALIAS Pbuf --
  // live ranges are disjoint (xpp: xproj_k8..xproj_reduce; Pbuf:
  // scanA..scanC) and 8*kM*kNPad*4 == kB*kNCH*kDI*kDS*4 exactly.
  constexpr size_t kWCache =
      2 * ((size_t)4096 * kD + (size_t)kD * kDI + (size_t)kNPad * kDI +
           (size_t)kDI * kDtRank) * 2 +
      ((size_t)kDFF * kD + (size_t)kD * kDFF) * 2;  // bf16 weights
  auto need = [](int nseg) -> size_t {
    const size_t mseg = (size_t)kM / nseg;
    size_t sz = kWCache + 4096;
    sz += (size_t)kM * kD * 2;            // h bf16
    sz += mseg * 4096 * 2;                // xz bf16 (aliases FFN hidden)
    sz += mseg * 2048 * 2;                // xs bf16
    sz += mseg * 128 * 2;                 // dbl bf16
    sz += mseg * 2048 * 2;                // dt bf16
    sz += 2 * (size_t)kB * kNCH * kDI * kDS * 4;  // Pbuf(+xpp alias) + Hbuf
    sz += (size_t)kB * kDI * kDS * 4;     // hstate
    sz += 2 * (size_t)kB * 3 * kDI * 2;   // conv tails
    sz += 32 * 256;                       // alignment slack
    return sz;
  };
  int nseg = 1;
  while (nseg <= 16 && need(nseg) > ws_size) nseg *= 2;
  if (nseg > 16) return;  // clean fail
  const int Lseg = kL / nseg;
  const int Mseg = kM / nseg;
  const int Lc = Lseg / kNCH;

  char* base = (char*)d_ws;
  size_t off = 0;
  auto alloc = [&](size_t bytes) {
    char* p = base + off;
    off = (off + bytes + 255) & ~(size_t)255;
    return p;
  };
  // bf16 weight cache
  u16* w_in[2], *w_out[2], *w_xp[2], *w_dt[2];
  for (int m = 0; m < 2; m++) {
    w_in[m]  = (u16*)alloc((size_t)4096 * kD * 2);
    w_out[m] = (u16*)alloc((size_t)kD * kDI * 2);
    w_xp[m]  = (u16*)alloc((size_t)kNPad * kDI * 2);
    w_dt[m]  = (u16*)alloc((size_t)kDI * kDtRank * 2);
  }
  u16* w_f1 = (u16*)alloc((size_t)kDFF * kD * 2);
  u16* w_f2 = (u16*)alloc((size_t)kD * kDFF * 2);
  // activations
  u16*   h      = (u16*)alloc((size_t)kM * kD * 2);
  u16*   xz     = (u16*)alloc((size_t)Mseg * 4096 * 2);
  u16*   xs     = (u16*)alloc((size_t)Mseg * 2048 * 2);
  u16*   dbl    = (u16*)alloc((size_t)Mseg * 128 * 2);
  u16*   dtb    = (u16*)alloc((size_t)Mseg * 2048 * 2);
  float* Pbuf   = (float*)alloc((size_t)kB * kNCH * kDI * kDS * 4);
  float* Hbuf   = (float*)alloc((size_t)kB * kNCH * kDI * kDS * 4);
  float* hstate = (float*)alloc((size_t)kB * kDI * kDS * 4);
  u16*   tail0  = (u16*)alloc((size_t)kB * 3 * kDI * 2);
  u16*   tail1  = (u16*)alloc((size_t)kB * 3 * kDI * 2);
  float* xpp    = Pbuf;   // alias: disjoint live ranges (see NOTE above)

  // fused weight conversion (once per call)
  {
    KJobs J;
    int b = 0, ji = 0;
    auto addjob = [&](const float* s, u16* d, int n4, int xp) {
      J.j[ji].s = s; J.j[ji].d = d; J.j[ji].n4 = n4;
      J.j[ji].blk0 = b; J.j[ji].xp = xp;
      b += (n4 + 255) >> 8;
      ji++;
    };
    for (int m = 0; m < 2; m++) {
      addjob(in_w[m],  w_in[m],  (4096 * kD) / 4, 0);
      addjob(out_w[m], w_out[m], (kD * kDI) / 4, 0);
      addjob(xproj_w[m], w_xp[m], (kNPad * kDI) / 4, 1);
      addjob(dt_w[m],  w_dt[m],  (kDI * kDtRank) / 4, 0);
    }
    addjob(ff1_w, w_f1, (kDFF * kD) / 4, 0);
    addjob(ff2_w, w_f2, (kD * kDFF) / 4, 0);
    cvt_all_kernel<<<b, 256, 0, stream>>>(J);
  }

  // LN(x) -> h (bf16)
  ln_kernel<<<kM, 256, 0, stream>>>(x, norm_g, norm_b, h);

  for (int m = 0; m < 2; m++) {
    for (int s = 0; s < nseg; s++) {
      const int l0 = s * Lseg;
      u16* tin  = (s & 1) ? tail0 : tail1;
      u16* tout = (s & 1) ? tail1 : tail0;
      // in_proj: h rows (REV for m=1) x in_w[4096,1024]^T -> xz [Mseg,4096]
      if (m == 0)
        gemm_mfma<128, 0, false, false, true, false, true, false>
            <<<dim3(Mseg / 128, 4096 / 128), 256, 0, stream>>>(
                h, kD, w_in[m], kD, xz, 4096, kD, nullptr, Lseg, l0);
      else
        gemm_mfma<128, 0, false, false, true, true, true, false>
            <<<dim3(Mseg / 128, 4096 / 128), 256, 0, stream>>>(
                h, kD, w_in[m], kD, xz, 4096, kD, nullptr, Lseg, l0);
      // causal depthwise conv + silu -> xs
      conv_silu_kernel<<<(Mseg * kDI) / 256, 256, 0, stream>>>(
          xz, conv_w[m], conv_b[m], xs, tin, tout, Lseg, l0);
      // x_proj: split-K x8 -> f32 partials (alias Pbuf) -> reduce to dbl
      xproj_k8_kernel<<<dim3(Mseg / 128, 8), 256, 0, stream>>>(
          xs, w_xp[m], xpp, Mseg);
      xproj_reduce_kernel<<<(Mseg * kNPad) / 256, 256, 0, stream>>>(
          xpp, dbl, Mseg * kNPad);
      // dt_proj + softplus: dedicated kernel
      dt_kernel<<<dim3(Mseg / 128, kDI / 128), 256, 0, stream>>>(
          dbl, w_dt[m], dt_b[m], dtb);
      // chunked scan: A (local), B (stitch), C (emit y into xs)
      scan_phaseA<<<dim3(kDI / 256, kNCH, kB), 256, 0, stream>>>(
          dtb, xs, dbl, Alog[m], Pbuf, Hbuf, Lseg, Lc);
      scan_phaseB<<<(kB * kDI * kDS) / 256, 256, 0, stream>>>(
          Pbuf, Hbuf, hstate, (s == 0) ? 1 : 0);
      scan_phaseC<<<dim3(kDI / 256, kNCH, kB), 256, 0, stream>>>(
          dtb, xs, dbl, xz, Alog[m], Dp[m], Pbuf, Lseg, Lc);
      // out_proj -> d_out rows (f32); m=1 accumulates (TILEN=64 2-phase)
      if (m == 0)
        gemm_mfma<64, 0, false, false, false, false, false, true>
            <<<dim3(Mseg / 128, kD / 64), 256, 0, stream>>>(
                xs, kDI, w_out[m], kDI, out, kD, kDI, nullptr, Lseg, l0);
      else
        gemm_mfma<64, 0, false, true, false, false, false, true>
            <<<dim3(Mseg / 128, kD / 64), 256, 0, stream>>>(
                xs, kDI, w_out[m], kDI, out, kD, kDI, nullptr, Lseg, l0);
    }
  }

  // x2 = x + gelu(fwd + bwd + x) in place on d_out; h = LN(x2) (fused)
  combine_ln_kernel<<<kM, 256, 0, stream>>>(x, out, ffn_g, ffn_b, h);

  // FFN: per M-segment: hidden = gelu(h@ff1^T+b1) (alias xz);
  // out += hidden@ff2^T + b2
  for (int s = 0; s < nseg; s++) {
    const int r0 = s * Mseg;
    gemm_mfma<128, 2, true, false, true, false, true, false>
        <<<dim3(Mseg / 128, kDFF / 128), 256, 0, stream>>>(
            h, kD, w_f1, kD, xz, kDFF, kD, ff1_b, Mseg, r0);
    gemm_mfma<64, 0, true, true, false, false, false, true>
        <<<dim3(Mseg / 128, kD / 64), 256, 0, stream>>>(
            xz, kDFF, w_f2, kDFF, out, kD, kDFF, ff2_b, Mseg, r0);
  }
}